// Round 1
// baseline (567.890 us; speedup 1.0000x reference)
//
#include <hip/hip_runtime.h>
#include <hip/hip_bf16.h>
#include <cstddef>

typedef __attribute__((ext_vector_type(8))) short short8;
typedef __attribute__((ext_vector_type(4))) float f32x4;

constexpr int CB = 2048;   // batch
constexpr int CD = 512;    // input dim
constexpr int CH = 2048;   // expert hidden
constexpr int CO = 512;    // output dim
constexpr int CE = 8;      // experts
constexpr int CR = 4;      // regimes

// ---------- helpers ----------
__device__ __forceinline__ float bs2f(short s){
  union { float f; unsigned u; } u; u.u = ((unsigned)(unsigned short)s) << 16; return u.f;
}
__device__ __forceinline__ short f2bs(float x){
  union { __hip_bfloat16 h; short s; } u; u.h = __float2bfloat16(x); return u.s;
}
__device__ __forceinline__ short8 pack8(const float* f){
  short8 r;
#pragma unroll
  for (int j = 0; j < 8; j++) r[j] = f2bs(f[j]);
  return r;
}
// byte offset inside a [128 rows][32 k] bf16 tile (64B rows), XOR-swizzled so that
// both b128 stage-writes and b128 fragment-reads spread evenly over the 8 bank-quads
__device__ __forceinline__ int swz(int row, int k){
  return row * 64 + (((k >> 3) ^ ((row >> 1) & 3)) << 4) + ((k & 7) << 1);
}

__device__ __forceinline__ void block_reduce2(float& a, float& b){
#pragma unroll
  for (int off = 32; off; off >>= 1){ a += __shfl_xor(a, off, 64); b += __shfl_xor(b, off, 64); }
  __shared__ float sa[4], sb[4];
  const int wid = threadIdx.x >> 6, lane = threadIdx.x & 63;
  __syncthreads();
  if (lane == 0){ sa[wid] = a; sb[wid] = b; }
  __syncthreads();
  a = sa[0] + sa[1] + sa[2] + sa[3];
  b = sb[0] + sb[1] + sb[2] + sb[3];
}

// ---------- regime bucketing ----------
__global__ void k_count(const int* __restrict__ regime, int* __restrict__ meta){
  int b = blockIdx.x * 256 + threadIdx.x;
  if (b < CB) atomicAdd(&meta[8 + regime[b]], 1);
}
__global__ void k_scan(int* meta){
  if (threadIdx.x == 0){
    int c0 = meta[8], c1 = meta[9], c2 = meta[10], c3 = meta[11];
    meta[0] = 0; meta[1] = c0; meta[2] = c0 + c1; meta[3] = c0 + c1 + c2; meta[4] = c0 + c1 + c2 + c3;
  }
}
__global__ void k_scatter(const int* __restrict__ regime, int* __restrict__ meta, int* __restrict__ perm){
  int b = blockIdx.x * 256 + threadIdx.x;
  if (b < CB){
    int r = regime[b];
    int pos = atomicAdd(&meta[12 + r], 1);
    perm[meta[r] + pos] = b;
  }
}

// ---------- f32 router GEMM (must be f32: top-k selection is discrete) ----------
// rh[i_sorted][H] = relu(x[perm[i]] @ rw1[r][:D] + rw1[r][D+r] + rb1[r])
__global__ __launch_bounds__(256) void k_router_f32(
    const float* __restrict__ x, const float* __restrict__ rw1, const float* __restrict__ rb1,
    const int* __restrict__ meta, const int* __restrict__ perm, float* __restrict__ rh){
  const int r = blockIdx.z;
  const int g0 = meta[r], Mg = meta[r + 1] - g0;
  const int m0 = blockIdx.y * 64;
  if (m0 >= Mg) return;
  const int n0 = blockIdx.x * 64;
  const float* W = rw1 + (size_t)r * (CD + CR) * CH;
  __shared__ float As[64][17];
  __shared__ float Bs[16][65];
  const int t = threadIdx.x;
  const int am = t >> 2, akq = (t & 3) * 4;
  const int bk = t >> 4, bnq = (t & 15) * 4;
  int ia = m0 + am; if (ia > Mg - 1) ia = Mg - 1;
  const float* arow = x + (size_t)perm[g0 + ia] * CD;
  const int tm = t >> 4, tn = t & 15;
  float acc[4][4];
#pragma unroll
  for (int a = 0; a < 4; a++)
#pragma unroll
    for (int b = 0; b < 4; b++) acc[a][b] = 0.f;
  for (int kk = 0; kk < CD; kk += 16){
    if (kk) __syncthreads();
    float4 av4 = *(const float4*)(arow + kk + akq);
    As[am][akq] = av4.x; As[am][akq + 1] = av4.y; As[am][akq + 2] = av4.z; As[am][akq + 3] = av4.w;
    float4 bv4 = *(const float4*)(W + (size_t)(kk + bk) * CH + n0 + bnq);
    Bs[bk][bnq] = bv4.x; Bs[bk][bnq + 1] = bv4.y; Bs[bk][bnq + 2] = bv4.z; Bs[bk][bnq + 3] = bv4.w;
    __syncthreads();
#pragma unroll
    for (int k = 0; k < 16; k++){
      float a0 = As[tm * 4 + 0][k], a1 = As[tm * 4 + 1][k], a2 = As[tm * 4 + 2][k], a3 = As[tm * 4 + 3][k];
      float b0 = Bs[k][tn * 4 + 0], b1 = Bs[k][tn * 4 + 1], b2 = Bs[k][tn * 4 + 2], b3 = Bs[k][tn * 4 + 3];
      acc[0][0] += a0 * b0; acc[0][1] += a0 * b1; acc[0][2] += a0 * b2; acc[0][3] += a0 * b3;
      acc[1][0] += a1 * b0; acc[1][1] += a1 * b1; acc[1][2] += a1 * b2; acc[1][3] += a1 * b3;
      acc[2][0] += a2 * b0; acc[2][1] += a2 * b1; acc[2][2] += a2 * b2; acc[2][3] += a2 * b3;
      acc[3][0] += a3 * b0; acc[3][1] += a3 * b1; acc[3][2] += a3 * b2; acc[3][3] += a3 * b3;
    }
  }
  const size_t biasoff = ((size_t)(r * (CD + CR) + CD + r)) * CH;  // one-hot row of rw1
#pragma unroll
  for (int jm = 0; jm < 4; jm++){
    const int mg = m0 + tm * 4 + jm;
    if (mg >= Mg) continue;
    const size_t orow = (size_t)(g0 + mg) * CH;
#pragma unroll
    for (int jn = 0; jn < 4; jn++){
      const int n = n0 + tn * 4 + jn;
      float v = acc[jm][jn] + rb1[(size_t)r * CH + n] + rw1[biasoff + n];
      rh[orow + n] = fmaxf(v, 0.f);
    }
  }
}

// ---------- logits + softmax + top-2 (f32) ----------
__global__ __launch_bounds__(256) void k_logits(
    const float* __restrict__ rh, const float* __restrict__ rw2, const float* __restrict__ rb2,
    const int* __restrict__ meta, const int* __restrict__ perm,
    int* __restrict__ tki, float* __restrict__ tkw){
  const int wid = threadIdx.x >> 6, lane = threadIdx.x & 63;
  const int i = blockIdx.x * 4 + wid;
  const int r = (i >= meta[1]) + (i >= meta[2]) + (i >= meta[3]);
  const float* w2 = rw2 + (size_t)r * CH * CE;
  const float* row = rh + (size_t)i * CH;
  float acc[CE];
#pragma unroll
  for (int e = 0; e < CE; e++) acc[e] = 0.f;
  for (int h = lane; h < CH; h += 64){
    const float rv = row[h];
    const float* wp = w2 + (size_t)h * CE;
#pragma unroll
    for (int e = 0; e < CE; e++) acc[e] += rv * wp[e];
  }
#pragma unroll
  for (int e = 0; e < CE; e++){
#pragma unroll
    for (int off = 32; off; off >>= 1) acc[e] += __shfl_xor(acc[e], off, 64);
    acc[e] += rb2[r * CE + e];
  }
  if (lane == 0){
    int i1 = 0; float m1 = acc[0];
#pragma unroll
    for (int e = 1; e < CE; e++) if (acc[e] > m1){ m1 = acc[e]; i1 = e; }
    int i2 = -1; float m2 = -1e30f;
#pragma unroll
    for (int e = 0; e < CE; e++) if (e != i1 && acc[e] > m2){ m2 = acc[e]; i2 = e; }
    const float e2 = __expf(m2 - m1);
    const float w1 = 1.f / (1.f + e2);
    const int b = perm[i];
    tki[b * 2] = i1; tki[b * 2 + 1] = i2;
    tkw[b * 2] = w1; tkw[b * 2 + 1] = e2 * w1;
  }
}

// ---------- generic MFMA bf16 GEMM, 128x128 tile, BK=32 ----------
// EPI: 1=expert GEMM1 (+eb1 -> hact), 2=expert GEMM2 (+eb2 +x residual, scatter -> eo),
//      3=QKV (+ipb -> qkv), 4=proj (+opb -> proj f32)
template<typename AT, bool WTR, int EPI>
__global__ __launch_bounds__(256) void gemm_k(
    const AT* __restrict__ A, long lda, long azstride,
    const int* __restrict__ rowmap,
    const float* __restrict__ W, long wstride, long ldw,
    const int* __restrict__ goff, int zdiv, int fixedM,
    int K, int N,
    float* __restrict__ outf, short* __restrict__ outb,
    const float* __restrict__ bias1, long b1s,
    const float* __restrict__ res,
    const int* __restrict__ operm){
  __shared__ __align__(16) char smem[16384];
  char* sA = smem;
  char* sB = smem + 8192;
  const int z = blockIdx.z;
  int g0, Mg;
  if (goff){ const int g = z / zdiv; g0 = goff[g]; Mg = goff[g + 1] - g0; }
  else { g0 = 0; Mg = fixedM; }
  const int m0 = blockIdx.y * 128;
  if (m0 >= Mg) return;
  const int n0 = blockIdx.x * 128;
  const AT* Ab = A;
  if constexpr (EPI == 2) Ab += (size_t)(z & 7) * (size_t)azstride;
  const float* Wb = W + (size_t)z * (size_t)wstride;

  const int tid = threadIdx.x;
  const int s_lr = tid >> 1;
  const int s_ch = (tid & 1) << 4;
  int i_s = m0 + s_lr; if (i_s > Mg - 1) i_s = Mg - 1;
  const long arow = rowmap ? (long)rowmap[g0 + i_s] : (long)(g0 + i_s);
  const AT* aptr = Ab + (size_t)arow * (size_t)lda + s_ch;

  const float* wptr;
  int bn_ = 0, bkh_ = 0;
  if constexpr (WTR){
    wptr = Wb + (size_t)(n0 + s_lr) * (size_t)ldw + s_ch;
  } else {
    bn_ = tid & 127; bkh_ = (tid >> 7) << 4;
    wptr = Wb + (size_t)bkh_ * (size_t)ldw + n0 + bn_;
  }

  const int lane = tid & 63, wid = tid >> 6;
  const int wm = (wid >> 1) << 6, wn = (wid & 1) << 6;
  const int r16 = lane & 15, kb = lane >> 4;

  f32x4 acc[4][4];
#pragma unroll
  for (int a = 0; a < 4; a++)
#pragma unroll
    for (int b = 0; b < 4; b++) acc[a][b] = (f32x4){0.f, 0.f, 0.f, 0.f};

  for (int k0 = 0; k0 < K; k0 += 32){
    if (k0) __syncthreads();
    { // stage A: [128 m][32 k] (f32->bf16 cvt or raw bf16)
      short8 s0, s1;
      if constexpr (sizeof(AT) == 4){
        float fb[16];
        const float4* p4 = (const float4*)(aptr + k0);
#pragma unroll
        for (int j = 0; j < 4; j++){ float4 f4 = p4[j]; fb[4*j] = f4.x; fb[4*j+1] = f4.y; fb[4*j+2] = f4.z; fb[4*j+3] = f4.w; }
        s0 = pack8(fb); s1 = pack8(fb + 8);
      } else {
        const short8* p8 = (const short8*)(aptr + k0);
        s0 = p8[0]; s1 = p8[1];
      }
      *(short8*)(sA + swz(s_lr, s_ch)) = s0;
      *(short8*)(sA + swz(s_lr, s_ch + 8)) = s1;
    }
    { // stage B: LDS holds [128 n][32 k]
      short8 s0, s1;
      if constexpr (WTR){      // W stored [N][K] (ipw/opw): k-contiguous rows
        float fb[16];
        const float4* p4 = (const float4*)(wptr + k0);
#pragma unroll
        for (int j = 0; j < 4; j++){ float4 f4 = p4[j]; fb[4*j] = f4.x; fb[4*j+1] = f4.y; fb[4*j+2] = f4.z; fb[4*j+3] = f4.w; }
        s0 = pack8(fb); s1 = pack8(fb + 8);
        *(short8*)(sB + swz(s_lr, s_ch)) = s0;
        *(short8*)(sB + swz(s_lr, s_ch + 8)) = s1;
      } else {                 // W stored [K][N] (ew1/ew2): strided gather, transpose into LDS
        float fb[16];
#pragma unroll
        for (int j = 0; j < 16; j++) fb[j] = wptr[(size_t)(k0 + j) * (size_t)ldw];
        s0 = pack8(fb); s1 = pack8(fb + 8);
        *(short8*)(sB + swz(bn_, bkh_)) = s0;
        *(short8*)(sB + swz(bn_, bkh_ + 8)) = s1;
      }
    }
    __syncthreads();
    short8 af[4], bfv[4];
#pragma unroll
    for (int mi = 0; mi < 4; mi++) af[mi] = *(const short8*)(sA + swz(wm + mi * 16 + r16, kb * 8));
#pragma unroll
    for (int ni = 0; ni < 4; ni++) bfv[ni] = *(const short8*)(sB + swz(wn + ni * 16 + r16, kb * 8));
#pragma unroll
    for (int mi = 0; mi < 4; mi++)
#pragma unroll
      for (int ni = 0; ni < 4; ni++)
        acc[mi][ni] = __builtin_amdgcn_mfma_f32_16x16x32_bf16(af[mi], bfv[ni], acc[mi][ni], 0, 0, 0);
  }

  const int e7 = z & 7;
#pragma unroll
  for (int mi = 0; mi < 4; mi++){
#pragma unroll
    for (int q = 0; q < 4; q++){
      const int i = m0 + wm + mi * 16 + kb * 4 + q;
      if (i >= Mg) continue;
#pragma unroll
      for (int ni = 0; ni < 4; ni++){
        const int n = n0 + wn + ni * 16 + r16;
        float v = acc[mi][ni][q];
        if constexpr (EPI == 1){
          v += bias1[(size_t)z * b1s + n];
          outb[((size_t)e7 * CB + (g0 + i)) * (size_t)N + n] = f2bs(v);
        } else if constexpr (EPI == 2){
          const int borig = operm[g0 + i];
          v += bias1[(size_t)z * b1s + n] + res[(size_t)borig * CD + n];
          outb[((size_t)borig * CE + e7) * (size_t)CO + n] = f2bs(v);
        } else if constexpr (EPI == 3){
          v += bias1[n];
          outb[(size_t)(g0 + i) * (size_t)N + n] = f2bs(v);
        } else {
          v += bias1[n];
          outf[(size_t)(g0 + i) * (size_t)N + n] = v;
        }
      }
    }
  }
}

// ---------- LN + relu over hact rows (in-place) ----------
__global__ __launch_bounds__(256) void k_ln(short* __restrict__ hact,
    const float* __restrict__ lng, const float* __restrict__ lnb, const int* __restrict__ meta){
  const int rowid = blockIdx.x;           // e*CB + i_sorted
  const int e = rowid >> 11, i = rowid & (CB - 1);
  const int r = (i >= meta[1]) + (i >= meta[2]) + (i >= meta[3]);
  short* p = hact + (size_t)rowid * CH;
  short8 raw = *(short8*)(p + threadIdx.x * 8);
  float v[8]; float s = 0.f, sq = 0.f;
#pragma unroll
  for (int j = 0; j < 8; j++){ v[j] = bs2f(raw[j]); s += v[j]; sq += v[j] * v[j]; }
  block_reduce2(s, sq);
  const float mean = s * (1.f / CH);
  const float var = sq * (1.f / CH) - mean * mean;
  const float rstd = rsqrtf(fmaxf(var, 0.f) + 1e-5f);
  const float* g = lng + ((size_t)r * CE + e) * CH;
  const float* bb = lnb + ((size_t)r * CE + e) * CH;
  short8 outv;
#pragma unroll
  for (int j = 0; j < 8; j++){
    const int h = threadIdx.x * 8 + j;
    const float val = (v[j] - mean) * rstd * g[h] + bb[h];
    outv[j] = f2bs(fmaxf(val, 0.f));
  }
  *(short8*)(p + threadIdx.x * 8) = outv;
}

// ---------- attention over expert axis, only for the 2 selected experts ----------
__global__ __launch_bounds__(128) void k_attn(const short* __restrict__ qkv,
    const int* __restrict__ tki, short* __restrict__ av){
  const int b = blockIdx.x;
  const int j = threadIdx.x >> 6, d = threadIdx.x & 63;
  const int s = tki[b * 2 + j];
  const short* base = qkv + (size_t)b * CE * 1536;
#pragma unroll
  for (int h = 0; h < 8; h++){
    const float qv = bs2f(base[(size_t)s * 1536 + h * 64 + d]);
    float sc[8];
#pragma unroll
    for (int e = 0; e < 8; e++){
      float pp = qv * bs2f(base[(size_t)e * 1536 + 512 + h * 64 + d]);
#pragma unroll
      for (int off = 32; off; off >>= 1) pp += __shfl_xor(pp, off, 64);
      sc[e] = pp * 0.125f;   // 1/sqrt(DH=64)
    }
    float m = sc[0];
#pragma unroll
    for (int e = 1; e < 8; e++) m = fmaxf(m, sc[e]);
    float den = 0.f, avd = 0.f;
#pragma unroll
    for (int e = 0; e < 8; e++){
      const float pe = __expf(sc[e] - m);
      den += pe;
      avd += pe * bs2f(base[(size_t)e * 1536 + 1024 + h * 64 + d]);
    }
    av[((size_t)b * 2 + j) * CO + h * 64 + d] = f2bs(avd / den);
  }
}

// ---------- final LN + top-k combine ----------
__global__ __launch_bounds__(256) void k_final(const short* __restrict__ eo,
    const float* __restrict__ proj, const int* __restrict__ tki, const float* __restrict__ tkw,
    const float* __restrict__ ang, const float* __restrict__ anb, float* __restrict__ out){
  const int b = blockIdx.x, t = threadIdx.x;
  float o0 = 0.f, o1 = 0.f;
#pragma unroll
  for (int j = 0; j < 2; j++){
    const int s = tki[b * 2 + j];
    const float w = tkw[b * 2 + j];
    const short* ep = eo + ((size_t)b * CE + s) * CO;
    const float* pp = proj + ((size_t)b * 2 + j) * CO;
    const float v0 = bs2f(ep[t]) + pp[t];
    const float v1 = bs2f(ep[t + 256]) + pp[t + 256];
    float sm = v0 + v1, sq = v0 * v0 + v1 * v1;
    block_reduce2(sm, sq);
    const float mean = sm * (1.f / CO);
    const float rstd = rsqrtf(fmaxf(sq * (1.f / CO) - mean * mean, 0.f) + 1e-5f);
    o0 += w * ((v0 - mean) * rstd * ang[t] + anb[t]);
    o1 += w * ((v1 - mean) * rstd * ang[t + 256] + anb[t + 256]);
  }
  out[(size_t)b * CO + t] = o0;
  out[(size_t)b * CO + t + 256] = o1;
}

// ---------- launch ----------
extern "C" void kernel_launch(void* const* d_in, const int* in_sizes, int n_in,
                              void* d_out, int out_size, void* d_ws, size_t ws_size,
                              hipStream_t stream){
  const float* x    = (const float*)d_in[0];
  const int*   regime = (const int*)d_in[1];
  // d_in[2] regime_features: redundant (== one_hot(regime)), folded into router bias
  const float* ew1  = (const float*)d_in[3];
  const float* eb1  = (const float*)d_in[4];
  const float* lng  = (const float*)d_in[5];
  const float* lnb  = (const float*)d_in[6];
  const float* ew2  = (const float*)d_in[7];
  const float* eb2  = (const float*)d_in[8];
  const float* rw1  = (const float*)d_in[9];
  const float* rb1  = (const float*)d_in[10];
  const float* rw2  = (const float*)d_in[11];
  const float* rb2  = (const float*)d_in[12];
  const float* ipw  = (const float*)d_in[13];
  const float* ipb  = (const float*)d_in[14];
  const float* opw  = (const float*)d_in[15];
  const float* opb  = (const float*)d_in[16];
  const float* ang  = (const float*)d_in[17];
  const float* anb  = (const float*)d_in[18];
  float* out = (float*)d_out;

  char* ws = (char*)d_ws;
  int*   meta = (int*)(ws);                       // [0..4] group offsets, [8..11] counts, [12..15] cursors
  int*   perm = (int*)(ws + (1u << 10));          // 8 KB
  int*   tki  = (int*)(ws + (16u << 10));         // 16 KB
  float* tkw  = (float*)(ws + (32u << 10));       // 16 KB
  float* rh   = (float*)(ws + (2ull << 20));      // f32 [CB][CH] = 16 MB
  short* eo   = (short*)(ws + (18ull << 20));     // bf16 [CB][CE][CO] = 16 MB
  short* av   = (short*)(ws + (34ull << 20));     // bf16 [CB*2][CO] = 4 MB
  float* proj = (float*)(ws + (40ull << 20));     // f32 [CB*2][CO] = 8 MB
  short* hact = (short*)(ws + (48ull << 20));     // bf16 [CE][CB][CH] = 64 MB
  short* qkv  = hact;                             // overlay: hact dead before QKV is written (48 MB)

  hipMemsetAsync(meta, 0, 1024, stream);
  k_count  <<<8, 256, 0, stream>>>(regime, meta);
  k_scan   <<<1, 64, 0, stream>>>(meta);
  k_scatter<<<8, 256, 0, stream>>>(regime, meta, perm);

  // f32 router GEMM (grouped by regime): rh = relu(x@rw1[:D] + onehot row + rb1)
  k_router_f32<<<dim3(32, 32, CR), 256, 0, stream>>>(x, rw1, rb1, meta, perm, rh);
  k_logits<<<CB / 4, 256, 0, stream>>>(rh, rw2, rb2, meta, perm, tki, tkw);

  // expert GEMM1: hact[e][i_sorted] = x@ew1[r,e] + eb1   (pre-LN)
  gemm_k<float, false, 1><<<dim3(16, 16, CR * CE), 256, 0, stream>>>(
      x, CD, 0, perm, ew1, (long)CD * CH, CH, meta, CE, 0, CD, CH,
      nullptr, hact, eb1, CH, nullptr, nullptr);
  k_ln<<<CE * CB, 256, 0, stream>>>(hact, lng, lnb, meta);

  // expert GEMM2: eo[b][e] = hact@ew2[r,e] + eb2 + x (scatter via perm)
  gemm_k<short, false, 2><<<dim3(4, 16, CR * CE), 256, 0, stream>>>(
      hact, CH, (long)CB * CH, nullptr, ew2, (long)CH * CO, CO, meta, CE, 0, CH, CO,
      nullptr, eo, eb2, CO, x, perm);

  // QKV: qkv[b*E+e] = eo@ipw^T + ipb
  gemm_k<short, true, 3><<<dim3(12, 128, 1), 256, 0, stream>>>(
      eo, CO, 0, nullptr, ipw, 0, CO, nullptr, 1, CB * CE, CO, 3 * CO,
      nullptr, qkv, ipb, 0, nullptr, nullptr);

  k_attn<<<CB, 128, 0, stream>>>(qkv, tki, av);

  // proj (selected experts only): proj[b*2+j] = av@opw^T + opb
  gemm_k<short, true, 4><<<dim3(4, 32, 1), 256, 0, stream>>>(
      av, CO, 0, nullptr, opw, 0, CO, nullptr, 1, CB * 2, CO, CO,
      proj, nullptr, opb, 0, nullptr, nullptr);

  k_final<<<CB, 256, 0, stream>>>(eo, proj, tki, tkw, ang, anb, out);
  (void)in_sizes; (void)n_in; (void)out_size; (void)ws_size;
}

// Round 2
// 541.563 us; speedup vs baseline: 1.0486x; 1.0486x over previous
//
#include <hip/hip_runtime.h>
#include <hip/hip_bf16.h>
#include <cstddef>

typedef __attribute__((ext_vector_type(8))) short short8;
typedef __attribute__((ext_vector_type(4))) float f32x4;

constexpr int CB = 2048;   // batch
constexpr int CD = 512;    // input dim
constexpr int CH = 2048;   // expert hidden
constexpr int CO = 512;    // output dim
constexpr int CE = 8;      // experts
constexpr int CR = 4;      // regimes

// ---------- helpers ----------
__device__ __forceinline__ float bs2f(short s){
  union { float f; unsigned u; } u; u.u = ((unsigned)(unsigned short)s) << 16; return u.f;
}
__device__ __forceinline__ short f2bs(float x){
  union { __hip_bfloat16 h; short s; } u; u.h = __float2bfloat16(x); return u.s;
}

#define GLL(g, l) __builtin_amdgcn_global_load_lds((const __attribute__((address_space(1))) void*)(g), (__attribute__((address_space(3))) void*)(l), 16, 0, 0)

__device__ __forceinline__ void block_reduce2(float& a, float& b){
#pragma unroll
  for (int off = 32; off; off >>= 1){ a += __shfl_xor(a, off, 64); b += __shfl_xor(b, off, 64); }
  __shared__ float sa[4], sb[4];
  const int wid = threadIdx.x >> 6, lane = threadIdx.x & 63;
  __syncthreads();
  if (lane == 0){ sa[wid] = a; sb[wid] = b; }
  __syncthreads();
  a = sa[0] + sa[1] + sa[2] + sa[3];
  b = sb[0] + sb[1] + sb[2] + sb[3];
}

// ---------- regime bucketing ----------
__global__ void k_count(const int* __restrict__ regime, int* __restrict__ meta){
  int b = blockIdx.x * 256 + threadIdx.x;
  if (b < CB) atomicAdd(&meta[8 + regime[b]], 1);
}
__global__ void k_scan(int* meta){
  if (threadIdx.x == 0){
    int c0 = meta[8], c1 = meta[9], c2 = meta[10], c3 = meta[11];
    meta[0] = 0; meta[1] = c0; meta[2] = c0 + c1; meta[3] = c0 + c1 + c2; meta[4] = c0 + c1 + c2 + c3;
  }
}
__global__ void k_scatter(const int* __restrict__ regime, int* __restrict__ meta, int* __restrict__ perm){
  int b = blockIdx.x * 256 + threadIdx.x;
  if (b < CB){
    int r = regime[b];
    int pos = atomicAdd(&meta[12 + r], 1);
    perm[meta[r] + pos] = b;
  }
}
// gather x rows into sorted order, convert to bf16
__global__ __launch_bounds__(256) void k_xperm(const float* __restrict__ x, const int* __restrict__ perm, short* __restrict__ xp){
  const int i = blockIdx.x;
  const int b = perm[i];
  const int c = threadIdx.x * 2;
  float2 v = *(const float2*)(x + (size_t)b * CD + c);
  short2 o; o.x = f2bs(v.x); o.y = f2bs(v.y);
  *(short2*)(xp + (size_t)i * CD + c) = o;
}
// plain f32 -> bf16 convert (layout preserved)
__global__ __launch_bounds__(256) void k_cvt(const float* __restrict__ in, short* __restrict__ outp, int n){
  int i = (blockIdx.x * 256 + threadIdx.x) * 8;
  if (i >= n) return;
  float4 a = *(const float4*)(in + i);
  float4 b = *(const float4*)(in + i + 4);
  short8 o;
  o[0]=f2bs(a.x); o[1]=f2bs(a.y); o[2]=f2bs(a.z); o[3]=f2bs(a.w);
  o[4]=f2bs(b.x); o[5]=f2bs(b.y); o[6]=f2bs(b.z); o[7]=f2bs(b.w);
  *(short8*)(outp + i) = o;
}
// f32 [K][N] -> bf16 [N][K] transpose+convert, per z matrix
__global__ __launch_bounds__(256) void k_cvt_t(const float* __restrict__ in, short* __restrict__ outp, int K, int N){
  __shared__ float tile[64][65];
  const int z = blockIdx.z;
  const int k0 = blockIdx.y * 64, n0 = blockIdx.x * 64;
  const float* src = in + (size_t)z * K * N;
  short* dst = outp + (size_t)z * K * N;
  const int t = threadIdx.x;
  const int kk = t >> 4, nq = (t & 15) * 4;
#pragma unroll
  for (int j = 0; j < 4; j++){
    float4 v = *(const float4*)(src + (size_t)(k0 + kk + j * 16) * N + n0 + nq);
    tile[kk + j * 16][nq] = v.x; tile[kk + j * 16][nq + 1] = v.y;
    tile[kk + j * 16][nq + 2] = v.z; tile[kk + j * 16][nq + 3] = v.w;
  }
  __syncthreads();
  const int n = t >> 2, kq = (t & 3) * 16;
  short8 o0, o1;
#pragma unroll
  for (int j = 0; j < 8; j++) o0[j] = f2bs(tile[kq + j][n]);
#pragma unroll
  for (int j = 0; j < 8; j++) o1[j] = f2bs(tile[kq + 8 + j][n]);
  short* drow = dst + (size_t)(n0 + n) * K + k0 + kq;
  *(short8*)(drow) = o0;
  *(short8*)(drow + 8) = o1;
}

// ---------- f32 router GEMM (must be f32: top-k selection is discrete) ----------
__global__ __launch_bounds__(256) void k_router_f32(
    const float* __restrict__ x, const float* __restrict__ rw1, const float* __restrict__ rb1,
    const int* __restrict__ meta, const int* __restrict__ perm, float* __restrict__ rh){
  const int r = blockIdx.z;
  const int g0 = meta[r], Mg = meta[r + 1] - g0;
  const int m0 = blockIdx.y * 64;
  if (m0 >= Mg) return;
  const int n0 = blockIdx.x * 64;
  const float* W = rw1 + (size_t)r * (CD + CR) * CH;
  __shared__ float As[64][17];
  __shared__ float Bs[16][65];
  const int t = threadIdx.x;
  const int am = t >> 2, akq = (t & 3) * 4;
  const int bk = t >> 4, bnq = (t & 15) * 4;
  int ia = m0 + am; if (ia > Mg - 1) ia = Mg - 1;
  const float* arow = x + (size_t)perm[g0 + ia] * CD;
  const int tm = t >> 4, tn = t & 15;
  float acc[4][4];
#pragma unroll
  for (int a = 0; a < 4; a++)
#pragma unroll
    for (int b = 0; b < 4; b++) acc[a][b] = 0.f;
  for (int kk = 0; kk < CD; kk += 16){
    if (kk) __syncthreads();
    float4 av4 = *(const float4*)(arow + kk + akq);
    As[am][akq] = av4.x; As[am][akq + 1] = av4.y; As[am][akq + 2] = av4.z; As[am][akq + 3] = av4.w;
    float4 bv4 = *(const float4*)(W + (size_t)(kk + bk) * CH + n0 + bnq);
    Bs[bk][bnq] = bv4.x; Bs[bk][bnq + 1] = bv4.y; Bs[bk][bnq + 2] = bv4.z; Bs[bk][bnq + 3] = bv4.w;
    __syncthreads();
#pragma unroll
    for (int k = 0; k < 16; k++){
      float a0 = As[tm * 4 + 0][k], a1 = As[tm * 4 + 1][k], a2 = As[tm * 4 + 2][k], a3 = As[tm * 4 + 3][k];
      float b0 = Bs[k][tn * 4 + 0], b1 = Bs[k][tn * 4 + 1], b2 = Bs[k][tn * 4 + 2], b3 = Bs[k][tn * 4 + 3];
      acc[0][0] += a0 * b0; acc[0][1] += a0 * b1; acc[0][2] += a0 * b2; acc[0][3] += a0 * b3;
      acc[1][0] += a1 * b0; acc[1][1] += a1 * b1; acc[1][2] += a1 * b2; acc[1][3] += a1 * b3;
      acc[2][0] += a2 * b0; acc[2][1] += a2 * b1; acc[2][2] += a2 * b2; acc[2][3] += a2 * b3;
      acc[3][0] += a3 * b0; acc[3][1] += a3 * b1; acc[3][2] += a3 * b2; acc[3][3] += a3 * b3;
    }
  }
  const size_t biasoff = ((size_t)(r * (CD + CR) + CD + r)) * CH;
#pragma unroll
  for (int jm = 0; jm < 4; jm++){
    const int mg = m0 + tm * 4 + jm;
    if (mg >= Mg) continue;
    const size_t orow = (size_t)(g0 + mg) * CH;
#pragma unroll
    for (int jn = 0; jn < 4; jn++){
      const int n = n0 + tn * 4 + jn;
      float v = acc[jm][jn] + rb1[(size_t)r * CH + n] + rw1[biasoff + n];
      rh[orow + n] = fmaxf(v, 0.f);
    }
  }
}

// ---------- logits + softmax + top-2 (f32) ----------
__global__ __launch_bounds__(256) void k_logits(
    const float* __restrict__ rh, const float* __restrict__ rw2, const float* __restrict__ rb2,
    const int* __restrict__ meta, const int* __restrict__ perm,
    int* __restrict__ tki, float* __restrict__ tkw){
  const int wid = threadIdx.x >> 6, lane = threadIdx.x & 63;
  const int i = blockIdx.x * 4 + wid;
  const int r = (i >= meta[1]) + (i >= meta[2]) + (i >= meta[3]);
  const float* w2 = rw2 + (size_t)r * CH * CE;
  const float* row = rh + (size_t)i * CH;
  float acc[CE];
#pragma unroll
  for (int e = 0; e < CE; e++) acc[e] = 0.f;
  for (int h = lane; h < CH; h += 64){
    const float rv = row[h];
    const float* wp = w2 + (size_t)h * CE;
#pragma unroll
    for (int e = 0; e < CE; e++) acc[e] += rv * wp[e];
  }
#pragma unroll
  for (int e = 0; e < CE; e++){
#pragma unroll
    for (int off = 32; off; off >>= 1) acc[e] += __shfl_xor(acc[e], off, 64);
    acc[e] += rb2[r * CE + e];
  }
  if (lane == 0){
    int i1 = 0; float m1 = acc[0];
#pragma unroll
    for (int e = 1; e < CE; e++) if (acc[e] > m1){ m1 = acc[e]; i1 = e; }
    int i2 = -1; float m2 = -1e30f;
#pragma unroll
    for (int e = 0; e < CE; e++) if (e != i1 && acc[e] > m2){ m2 = acc[e]; i2 = e; }
    const float e2 = __expf(m2 - m1);
    const float w1 = 1.f / (1.f + e2);
    const int b = perm[i];
    tki[b * 2] = i1; tki[b * 2 + 1] = i2;
    tkw[b * 2] = w1; tkw[b * 2 + 1] = e2 * w1;
  }
}
__global__ void k_qrows(const int* __restrict__ tki, int* __restrict__ qrows){
  int i = blockIdx.x * 256 + threadIdx.x;
  if (i < CB * 2) qrows[i] = (i >> 1) * CE + tki[i];
}

// ---------- bf16 MFMA GEMM, 128x128 tile, BK=32, global_load_lds, 2-phase dbuf ----------
// B is bf16 [z][N][K] (k-contiguous rows). A is bf16 [.][K].
// EPI: 1 = expert GEMM1 (+eb1 -> hact bf16, sorted rows)
//      2 = expert GEMM2 (+eb2 + xp residual, scatter via operm -> eo bf16)
//      3 = plain bf16 out (+bias); optional A row-gather via operm
//      4 = plain f32 out (+bias)
template<int EPI>
__global__ __launch_bounds__(256) void gemm_bf16(
    const short* __restrict__ A, const short* __restrict__ Wt,
    const int* __restrict__ goff, int fixedM, int K, int N,
    const float* __restrict__ bias, long bstride,
    short* __restrict__ outb, float* __restrict__ outf,
    const short* __restrict__ res, const int* __restrict__ operm){
  constexpr int BK = 32;
  __shared__ __align__(16) short lds[2][8192];   // per buf: A 4096 | B 4096 shorts (32 KB total)

  const int z = blockIdx.z;
  int g0 = 0, Mg = fixedM;
  if (goff){ const int r = z >> 3; g0 = goff[r]; Mg = goff[r + 1] - g0; }
  const int m0 = blockIdx.y * 128;
  if (m0 >= Mg) return;
  const int n0 = blockIdx.x * 128;
  const int e = z & 7;

  const short* Ab;
  if constexpr (EPI == 2) Ab = A + ((size_t)e * CB + g0) * (size_t)K;
  else if constexpr (EPI == 1) Ab = A + (size_t)g0 * (size_t)K;
  else Ab = A;
  const short* Wb = Wt + (size_t)z * (size_t)N * (size_t)K;

  const int tid = threadIdx.x;
  const int lane = tid & 63, wid = tid >> 6;
  const int srow = lane >> 2;            // 0..15 rows within a 16-row segment
  const int skc = (lane & 3) * 8;        // k chunk (8 bf16 = 16 B)

  int ar0 = m0 + wid * 32 + srow;
  int ar1 = ar0 + 16;
  if (ar0 > Mg - 1) ar0 = Mg - 1;
  if (ar1 > Mg - 1) ar1 = Mg - 1;
  if constexpr (EPI == 3){
    if (operm){ ar0 = operm[ar0]; ar1 = operm[ar1]; }
  }
  const short* ga0 = Ab + (size_t)ar0 * K + skc;
  const short* ga1 = Ab + (size_t)ar1 * K + skc;
  const int brow = n0 + wid * 32 + srow;
  const short* gb0 = Wb + (size_t)brow * K + skc;
  const short* gb1 = gb0 + (size_t)16 * K;

  const int wm = (wid >> 1) * 64, wn = (wid & 1) * 64;
  const int r16 = lane & 15, kb = lane >> 4;

  f32x4 acc[4][4];
#pragma unroll
  for (int a = 0; a < 4; a++)
#pragma unroll
    for (int b = 0; b < 4; b++) acc[a][b] = (f32x4){0.f, 0.f, 0.f, 0.f};

  const int NT = K / BK;
  int buf = 0;

  // prologue: stage tile 0
  {
    short* dA = &lds[0][0] + wid * 1024;
    short* dB = &lds[0][4096] + wid * 1024;
    GLL(ga0, dA); GLL(ga1, dA + 512);
    GLL(gb0, dB); GLL(gb1, dB + 512);
  }
  __syncthreads();

  for (int t = 0; t < NT; ++t){
    if (t + 1 < NT){
      const int kof = (t + 1) * BK;
      short* dA = &lds[buf ^ 1][0] + wid * 1024;
      short* dB = &lds[buf ^ 1][4096] + wid * 1024;
      GLL(ga0 + kof, dA); GLL(ga1 + kof, dA + 512);
      GLL(gb0 + kof, dB); GLL(gb1 + kof, dB + 512);
    }
    const short* sA = &lds[buf][0];
    const short* sB = &lds[buf][4096];
    short8 af[4], bfv[4];
#pragma unroll
    for (int mi = 0; mi < 4; mi++) af[mi] = *(const short8*)(sA + (wm + mi * 16 + r16) * 32 + kb * 8);
#pragma unroll
    for (int ni = 0; ni < 4; ni++) bfv[ni] = *(const short8*)(sB + (wn + ni * 16 + r16) * 32 + kb * 8);
#pragma unroll
    for (int mi = 0; mi < 4; mi++)
#pragma unroll
      for (int ni = 0; ni < 4; ni++)
        acc[mi][ni] = __builtin_amdgcn_mfma_f32_16x16x32_bf16(af[mi], bfv[ni], acc[mi][ni], 0, 0, 0);
    __syncthreads();
    buf ^= 1;
  }

#pragma unroll
  for (int mi = 0; mi < 4; mi++){
#pragma unroll
    for (int q = 0; q < 4; q++){
      const int i = m0 + wm + mi * 16 + kb * 4 + q;
      if (i >= Mg) continue;
#pragma unroll
      for (int ni = 0; ni < 4; ni++){
        const int n = n0 + wn + ni * 16 + r16;
        float v = acc[mi][ni][q] + bias[(size_t)z * bstride + n];
        if constexpr (EPI == 1){
          outb[((size_t)e * CB + (g0 + i)) * (size_t)N + n] = f2bs(v);
        } else if constexpr (EPI == 2){
          const int borig = operm[g0 + i];
          v += bs2f(res[(size_t)(g0 + i) * CD + n]);
          outb[((size_t)borig * CE + e) * (size_t)CO + n] = f2bs(v);
        } else if constexpr (EPI == 3){
          outb[(size_t)i * (size_t)N + n] = f2bs(v);
        } else {
          outf[(size_t)i * (size_t)N + n] = v;
        }
      }
    }
  }
}

// ---------- LN + relu over hact rows (in-place) ----------
__global__ __launch_bounds__(256) void k_ln(short* __restrict__ hact,
    const float* __restrict__ lng, const float* __restrict__ lnb, const int* __restrict__ meta){
  const int rowid = blockIdx.x;           // e*CB + i_sorted
  const int e = rowid >> 11, i = rowid & (CB - 1);
  const int r = (i >= meta[1]) + (i >= meta[2]) + (i >= meta[3]);
  short* p = hact + (size_t)rowid * CH;
  short8 raw = *(short8*)(p + threadIdx.x * 8);
  float v[8]; float s = 0.f, sq = 0.f;
#pragma unroll
  for (int j = 0; j < 8; j++){ v[j] = bs2f(raw[j]); s += v[j]; sq += v[j] * v[j]; }
  block_reduce2(s, sq);
  const float mean = s * (1.f / CH);
  const float var = sq * (1.f / CH) - mean * mean;
  const float rstd = rsqrtf(fmaxf(var, 0.f) + 1e-5f);
  const float* g = lng + ((size_t)r * CE + e) * CH;
  const float* bb = lnb + ((size_t)r * CE + e) * CH;
  short8 outv;
#pragma unroll
  for (int j = 0; j < 8; j++){
    const int h = threadIdx.x * 8 + j;
    const float val = (v[j] - mean) * rstd * g[h] + bb[h];
    outv[j] = f2bs(fmaxf(val, 0.f));
  }
  *(short8*)(p + threadIdx.x * 8) = outv;
}

// ---------- attention over expert axis (q only for the 2 selected experts) ----------
__global__ __launch_bounds__(128) void k_attn(const short* __restrict__ qb, const short* __restrict__ kv,
    const int* __restrict__ tki, short* __restrict__ av){
  const int b = blockIdx.x;
  const int j = threadIdx.x >> 6, d = threadIdx.x & 63;
  const short* q = qb + (size_t)(b * 2 + j) * CO;
  const short* base = kv + (size_t)b * CE * 1024;
#pragma unroll
  for (int h = 0; h < 8; h++){
    const float qv = bs2f(q[h * 64 + d]);
    float sc[8];
#pragma unroll
    for (int e = 0; e < 8; e++){
      float pp = qv * bs2f(base[(size_t)e * 1024 + h * 64 + d]);
#pragma unroll
      for (int off = 32; off; off >>= 1) pp += __shfl_xor(pp, off, 64);
      sc[e] = pp * 0.125f;   // 1/sqrt(DH=64)
    }
    float m = sc[0];
#pragma unroll
    for (int e = 1; e < 8; e++) m = fmaxf(m, sc[e]);
    float den = 0.f, avd = 0.f;
#pragma unroll
    for (int e = 0; e < 8; e++){
      const float pe = __expf(sc[e] - m);
      den += pe;
      avd += pe * bs2f(base[(size_t)e * 1024 + 512 + h * 64 + d]);
    }
    av[((size_t)b * 2 + j) * CO + h * 64 + d] = f2bs(avd / den);
  }
}

// ---------- final LN + top-k combine ----------
__global__ __launch_bounds__(256) void k_final(const short* __restrict__ eo,
    const float* __restrict__ proj, const int* __restrict__ tki, const float* __restrict__ tkw,
    const float* __restrict__ ang, const float* __restrict__ anb, float* __restrict__ out){
  const int b = blockIdx.x, t = threadIdx.x;
  float o0 = 0.f, o1 = 0.f;
#pragma unroll
  for (int j = 0; j < 2; j++){
    const int s = tki[b * 2 + j];
    const float w = tkw[b * 2 + j];
    const short* ep = eo + ((size_t)b * CE + s) * CO;
    const float* pp = proj + ((size_t)b * 2 + j) * CO;
    const float v0 = bs2f(ep[t]) + pp[t];
    const float v1 = bs2f(ep[t + 256]) + pp[t + 256];
    float sm = v0 + v1, sq = v0 * v0 + v1 * v1;
    block_reduce2(sm, sq);
    const float mean = sm * (1.f / CO);
    const float rstd = rsqrtf(fmaxf(sq * (1.f / CO) - mean * mean, 0.f) + 1e-5f);
    o0 += w * ((v0 - mean) * rstd * ang[t] + anb[t]);
    o1 += w * ((v1 - mean) * rstd * ang[t + 256] + anb[t + 256]);
  }
  out[(size_t)b * CO + t] = o0;
  out[(size_t)b * CO + t + 256] = o1;
}

// ---------- launch ----------
extern "C" void kernel_launch(void* const* d_in, const int* in_sizes, int n_in,
                              void* d_out, int out_size, void* d_ws, size_t ws_size,
                              hipStream_t stream){
  const float* x    = (const float*)d_in[0];
  const int*   regime = (const int*)d_in[1];
  const float* ew1  = (const float*)d_in[3];
  const float* eb1  = (const float*)d_in[4];
  const float* lng  = (const float*)d_in[5];
  const float* lnb  = (const float*)d_in[6];
  const float* ew2  = (const float*)d_in[7];
  const float* eb2  = (const float*)d_in[8];
  const float* rw1  = (const float*)d_in[9];
  const float* rb1  = (const float*)d_in[10];
  const float* rw2  = (const float*)d_in[11];
  const float* rb2  = (const float*)d_in[12];
  const float* ipw  = (const float*)d_in[13];
  const float* ipb  = (const float*)d_in[14];
  const float* opw  = (const float*)d_in[15];
  const float* opb  = (const float*)d_in[16];
  const float* ang  = (const float*)d_in[17];
  const float* anb  = (const float*)d_in[18];
  float* out = (float*)d_out;

  char* ws = (char*)d_ws;
  // workspace layout (total 166 MB):
  int*   meta  = (int*)(ws);                      // 1 KB used
  int*   perm  = (int*)(ws + (16u << 10));
  int*   tki   = (int*)(ws + (32u << 10));
  float* tkw   = (float*)(ws + (64u << 10));
  int*   qrows = (int*)(ws + (96u << 10));
  short* xp    = (short*)(ws + (1ull << 20));     // bf16 [2048][512] sorted = 2 MB
  short* ipwb  = (short*)(ws + (3ull << 20));     // bf16 [1536][512] = 1.5 MB
  short* opwb  = (short*)(ws + (5ull << 20));     // bf16 [512][512] = 0.5 MB
  float* rh    = (float*)(ws + (6ull << 20));     // f32 [2048][2048] = 16 MB (dead after k_logits)
  short* qb    = (short*)(ws + (6ull << 20));     // bf16 [4096][512] = 4 MB (overlays rh)
  float* proj  = (float*)(ws + (10ull << 20));    // f32 [4096][512] = 8 MB (overlays rh)
  short* av    = (short*)(ws + (18ull << 20));    // bf16 [4096][512] = 4 MB (overlays rh)
  short* hact  = (short*)(ws + (22ull << 20));    // bf16 [8][2048][2048] = 64 MB
  short* qkv   = hact;                            // bf16 [16384][1024] = 32 MB (hact dead)
  short* wt    = (short*)(ws + (86ull << 20));    // bf16 [32][N][K] = 64 MB (ew1t then ew2t)
  short* eo    = (short*)(ws + (150ull << 20));   // bf16 [2048][8][512] = 16 MB

  hipMemsetAsync(meta, 0, 1024, stream);
  k_count  <<<8, 256, 0, stream>>>(regime, meta);
  k_scan   <<<1, 64, 0, stream>>>(meta);
  k_scatter<<<8, 256, 0, stream>>>(regime, meta, perm);
  k_xperm  <<<CB, 256, 0, stream>>>(x, perm, xp);
  k_cvt    <<<384, 256, 0, stream>>>(ipw, ipwb, 1536 * 512);
  k_cvt    <<<128, 256, 0, stream>>>(opw, opwb, 512 * 512);

  // router (f32) + top-2
  k_router_f32<<<dim3(32, 32, CR), 256, 0, stream>>>(x, rw1, rb1, meta, perm, rh);
  k_logits<<<CB / 4, 256, 0, stream>>>(rh, rw2, rb2, meta, perm, tki, tkw);
  k_qrows<<<16, 256, 0, stream>>>(tki, qrows);

  // expert GEMM1: hact[e][i_sorted] = xp @ ew1t[r,e] + eb1
  k_cvt_t<<<dim3(32, 8, 32), 256, 0, stream>>>(ew1, wt, CD, CH);
  gemm_bf16<1><<<dim3(16, 16, CR * CE), 256, 0, stream>>>(
      xp, wt, meta, 0, CD, CH, eb1, CH, hact, nullptr, nullptr, nullptr);
  k_ln<<<CE * CB, 256, 0, stream>>>(hact, lng, lnb, meta);

  // expert GEMM2: eo[borig][e] = hact @ ew2t[r,e] + eb2 + xp
  k_cvt_t<<<dim3(8, 32, 32), 256, 0, stream>>>(ew2, wt, CH, CO);
  gemm_bf16<2><<<dim3(4, 16, CR * CE), 256, 0, stream>>>(
      hact, wt, meta, 0, CH, CO, eb2, CO, eo, nullptr, xp, perm);

  // KV for all (b,e): qkv[row][1024] = eo @ ipwb[512:1536] + ipb[512:]
  gemm_bf16<3><<<dim3(8, 128, 1), 256, 0, stream>>>(
      eo, ipwb + (size_t)512 * 512, nullptr, CB * CE, CO, 1024, ipb + 512, 0, qkv, nullptr, nullptr, nullptr);
  // Q only for selected experts: qb[b*2+j] = eo[qrows] @ ipwb[0:512] + ipb[:512]
  gemm_bf16<3><<<dim3(4, 32, 1), 256, 0, stream>>>(
      eo, ipwb, nullptr, CB * 2, CO, CO, ipb, 0, qb, nullptr, nullptr, qrows);

  k_attn<<<CB, 128, 0, stream>>>(qb, qkv, tki, av);

  // proj: proj[b*2+j] = av @ opwb + opb   (f32 out)
  gemm_bf16<4><<<dim3(4, 32, 1), 256, 0, stream>>>(
      av, opwb, nullptr, CB * 2, CO, CO, opb, 0, nullptr, proj, nullptr, nullptr);

  k_final<<<CB, 256, 0, stream>>>(eo, proj, tki, tkw, ang, anb, out);
  (void)in_sizes; (void)n_in; (void)out_size; (void)ws_size;
}

// Round 3
// 498.604 us; speedup vs baseline: 1.1390x; 1.0862x over previous
//
#include <hip/hip_runtime.h>
#include <hip/hip_bf16.h>
#include <cstddef>

typedef __attribute__((ext_vector_type(8))) short short8;
typedef __attribute__((ext_vector_type(4))) float f32x4;

constexpr int CB = 2048;   // batch
constexpr int CD = 512;    // input dim
constexpr int CH = 2048;   // expert hidden
constexpr int CO = 512;    // output dim
constexpr int CE = 8;      // experts
constexpr int CR = 4;      // regimes

// ---------- helpers ----------
__device__ __forceinline__ float bs2f(short s){
  union { float f; unsigned u; } u; u.u = ((unsigned)(unsigned short)s) << 16; return u.f;
}
__device__ __forceinline__ short f2bs(float x){
  union { __hip_bfloat16 h; short s; } u; u.h = __float2bfloat16(x); return u.s;
}

#define GLL(g, l) __builtin_amdgcn_global_load_lds((const __attribute__((address_space(1))) void*)(g), (__attribute__((address_space(3))) void*)(l), 16, 0, 0)

__device__ __forceinline__ void block_reduce2(float& a, float& b){
#pragma unroll
  for (int off = 32; off; off >>= 1){ a += __shfl_xor(a, off, 64); b += __shfl_xor(b, off, 64); }
  __shared__ float sa[4], sb[4];
  const int wid = threadIdx.x >> 6, lane = threadIdx.x & 63;
  __syncthreads();
  if (lane == 0){ sa[wid] = a; sb[wid] = b; }
  __syncthreads();
  a = sa[0] + sa[1] + sa[2] + sa[3];
  b = sb[0] + sb[1] + sb[2] + sb[3];
}

// ---------- regime bucketing ----------
__global__ void k_count(const int* __restrict__ regime, int* __restrict__ meta){
  int b = blockIdx.x * 256 + threadIdx.x;
  if (b < CB) atomicAdd(&meta[8 + regime[b]], 1);
}
__global__ void k_scan(int* meta){
  if (threadIdx.x == 0){
    int c0 = meta[8], c1 = meta[9], c2 = meta[10], c3 = meta[11];
    meta[0] = 0; meta[1] = c0; meta[2] = c0 + c1; meta[3] = c0 + c1 + c2; meta[4] = c0 + c1 + c2 + c3;
  }
}
__global__ void k_scatter(const int* __restrict__ regime, int* __restrict__ meta, int* __restrict__ perm){
  int b = blockIdx.x * 256 + threadIdx.x;
  if (b < CB){
    int r = regime[b];
    int pos = atomicAdd(&meta[12 + r], 1);
    perm[meta[r] + pos] = b;
  }
}

// gather x rows into sorted order; write bf16 hi (xp) and duplicated hi/lo router A' (xd)
__global__ __launch_bounds__(256) void k_xsplit(const float* __restrict__ x, const int* __restrict__ perm,
                                                short* __restrict__ xp, short* __restrict__ xd){
  const int i = blockIdx.x;
  const int b = perm[i];
  const int c = threadIdx.x * 2;
  float2 v = *(const float2*)(x + (size_t)b * CD + c);
  short2 hi; hi.x = f2bs(v.x); hi.y = f2bs(v.y);
  short2 lo; lo.x = f2bs(v.x - bs2f(hi.x)); lo.y = f2bs(v.y - bs2f(hi.y));
  *(short2*)(xp + (size_t)i * CD + c) = hi;
  short* row = xd + (size_t)i * 2048;
  *(short2*)(row + c) = hi;
  *(short2*)(row + 512 + c) = hi;
  *(short2*)(row + 1024 + c) = lo;
  *(short2*)(row + 1536 + c) = lo;
}

// plain f32 -> bf16 convert (layout preserved)
__global__ __launch_bounds__(256) void k_cvt(const float* __restrict__ in, short* __restrict__ outp, int n){
  int i = (blockIdx.x * 256 + threadIdx.x) * 8;
  if (i >= n) return;
  float4 a = *(const float4*)(in + i);
  float4 b = *(const float4*)(in + i + 4);
  short8 o;
  o[0]=f2bs(a.x); o[1]=f2bs(a.y); o[2]=f2bs(a.z); o[3]=f2bs(a.w);
  o[4]=f2bs(b.x); o[5]=f2bs(b.y); o[6]=f2bs(b.z); o[7]=f2bs(b.w);
  *(short8*)(outp + i) = o;
}

// f32 [K][N] -> bf16 [N][K] transpose+convert, per z matrix
__global__ __launch_bounds__(256) void k_cvt_t(const float* __restrict__ in, short* __restrict__ outp, int K, int N){
  __shared__ float tile[64][65];
  const int z = blockIdx.z;
  const int k0 = blockIdx.y * 64, n0 = blockIdx.x * 64;
  const float* src = in + (size_t)z * K * N;
  short* dst = outp + (size_t)z * K * N;
  const int t = threadIdx.x;
  const int kk = t >> 4, nq = (t & 15) * 4;
#pragma unroll
  for (int j = 0; j < 4; j++){
    float4 v = *(const float4*)(src + (size_t)(k0 + kk + j * 16) * N + n0 + nq);
    tile[kk + j * 16][nq] = v.x; tile[kk + j * 16][nq + 1] = v.y;
    tile[kk + j * 16][nq + 2] = v.z; tile[kk + j * 16][nq + 3] = v.w;
  }
  __syncthreads();
  const int n = t >> 2, kq = (t & 3) * 16;
  short8 o0, o1;
#pragma unroll
  for (int j = 0; j < 8; j++) o0[j] = f2bs(tile[kq + j][n]);
#pragma unroll
  for (int j = 0; j < 8; j++) o1[j] = f2bs(tile[kq + 8 + j][n]);
  short* drow = dst + (size_t)(n0 + n) * K + k0 + kq;
  *(short8*)(drow) = o0;
  *(short8*)(drow + 8) = o1;
}

// rw1 [r][512..][2048] f32 -> router B' [r][n][2048] bf16 = [Whi | Wlo | Whi | Wlo]
__global__ __launch_bounds__(256) void k_rwt(const float* __restrict__ rw1, short* __restrict__ Bp){
  __shared__ float tile[64][65];
  const int r = blockIdx.z;
  const int k0 = blockIdx.y * 64, n0 = blockIdx.x * 64;
  const float* src = rw1 + (size_t)r * (CD + CR) * CH;
  short* dst = Bp + (size_t)r * CH * 2048;
  const int t = threadIdx.x;
  const int kk = t >> 4, nq = (t & 15) * 4;
#pragma unroll
  for (int j = 0; j < 4; j++){
    float4 v = *(const float4*)(src + (size_t)(k0 + kk + j * 16) * CH + n0 + nq);
    tile[kk + j * 16][nq] = v.x; tile[kk + j * 16][nq + 1] = v.y;
    tile[kk + j * 16][nq + 2] = v.z; tile[kk + j * 16][nq + 3] = v.w;
  }
  __syncthreads();
  const int n = t >> 2, kq = (t & 3) * 16;
  short8 h0, h1, l0, l1;
#pragma unroll
  for (int j = 0; j < 8; j++){
    float f = tile[kq + j][n];
    short h = f2bs(f); h0[j] = h; l0[j] = f2bs(f - bs2f(h));
  }
#pragma unroll
  for (int j = 0; j < 8; j++){
    float f = tile[kq + 8 + j][n];
    short h = f2bs(f); h1[j] = h; l1[j] = f2bs(f - bs2f(h));
  }
  short* drow = dst + (size_t)(n0 + n) * 2048;
  *(short8*)(drow + k0 + kq) = h0;        *(short8*)(drow + k0 + kq + 8) = h1;
  *(short8*)(drow + 512 + k0 + kq) = l0;  *(short8*)(drow + 512 + k0 + kq + 8) = l1;
  *(short8*)(drow + 1024 + k0 + kq) = h0; *(short8*)(drow + 1024 + k0 + kq + 8) = h1;
  *(short8*)(drow + 1536 + k0 + kq) = l0; *(short8*)(drow + 1536 + k0 + kq + 8) = l1;
}

// rbias[r][n] = rb1[r][n] + rw1[r][512+r][n]   (one-hot row folded in, f32)
__global__ void k_rbias(const float* __restrict__ rw1, const float* __restrict__ rb1, float* __restrict__ rbias){
  const int r = blockIdx.y, n = blockIdx.x * 256 + threadIdx.x;
  rbias[r * CH + n] = rb1[(size_t)r * CH + n] + rw1[((size_t)r * (CD + CR) + CD + r) * CH + n];
}

// ---------- logits + softmax + top-2 (f32) ----------
__global__ __launch_bounds__(256) void k_logits(
    const float* __restrict__ rh, const float* __restrict__ rw2, const float* __restrict__ rb2,
    const int* __restrict__ meta, const int* __restrict__ perm,
    int* __restrict__ tki, float* __restrict__ tkw){
  const int wid = threadIdx.x >> 6, lane = threadIdx.x & 63;
  const int i = blockIdx.x * 4 + wid;
  const int r = (i >= meta[1]) + (i >= meta[2]) + (i >= meta[3]);
  const float* w2 = rw2 + (size_t)r * CH * CE;
  const float* row = rh + (size_t)i * CH;
  float acc[CE];
#pragma unroll
  for (int e = 0; e < CE; e++) acc[e] = 0.f;
  for (int h = lane; h < CH; h += 64){
    const float rv = row[h];
    const float* wp = w2 + (size_t)h * CE;
#pragma unroll
    for (int e = 0; e < CE; e++) acc[e] += rv * wp[e];
  }
#pragma unroll
  for (int e = 0; e < CE; e++){
#pragma unroll
    for (int off = 32; off; off >>= 1) acc[e] += __shfl_xor(acc[e], off, 64);
    acc[e] += rb2[r * CE + e];
  }
  if (lane == 0){
    int i1 = 0; float m1 = acc[0];
#pragma unroll
    for (int e = 1; e < CE; e++) if (acc[e] > m1){ m1 = acc[e]; i1 = e; }
    int i2 = -1; float m2 = -1e30f;
#pragma unroll
    for (int e = 0; e < CE; e++) if (e != i1 && acc[e] > m2){ m2 = acc[e]; i2 = e; }
    const float e2 = __expf(m2 - m1);
    const float w1 = 1.f / (1.f + e2);
    const int b = perm[i];
    tki[b * 2] = i1; tki[b * 2 + 1] = i2;
    tkw[b * 2] = w1; tkw[b * 2 + 1] = e2 * w1;
  }
}
__global__ void k_qrows(const int* __restrict__ tki, int* __restrict__ qrows){
  int i = blockIdx.x * 256 + threadIdx.x;
  if (i < CB * 2) qrows[i] = (i >> 1) * CE + tki[i];
}

// ---------- bf16 MFMA GEMM, 128x128 tile, BK=32, global_load_lds, 2-phase dbuf ----------
// B is bf16 [z][N][K] (k-contiguous rows). A is bf16 [.][K].
// EPI: 1 = expert GEMM1 (+eb1 -> hact bf16, sorted rows; group r = z>>3)
//      2 = expert GEMM2 (+eb2 + xp residual, scatter via operm -> eo bf16; group r = z>>3)
//      3 = plain bf16 out (+bias); optional A row-gather via operm
//      4 = plain f32 out (+bias)
//      5 = router (+bias[z], relu, f32 out; group r = z)
template<int EPI>
__global__ __launch_bounds__(256) void gemm_bf16(
    const short* __restrict__ A, const short* __restrict__ Wt,
    const int* __restrict__ goff, int fixedM, int K, int N,
    const float* __restrict__ bias, long bstride,
    short* __restrict__ outb, float* __restrict__ outf,
    const short* __restrict__ res, const int* __restrict__ operm){
  constexpr int BK = 32;
  __shared__ __align__(16) short lds[2][8192];   // per buf: A 4096 | B 4096 shorts (32 KB total)

  const int z = blockIdx.z;
  int g0 = 0, Mg = fixedM;
  if (goff){ const int r = (EPI == 5) ? z : (z >> 3); g0 = goff[r]; Mg = goff[r + 1] - g0; }
  const int m0 = blockIdx.y * 128;
  if (m0 >= Mg) return;
  const int n0 = blockIdx.x * 128;
  const int e = z & 7;

  const short* Ab;
  if constexpr (EPI == 2) Ab = A + ((size_t)e * CB + g0) * (size_t)K;
  else if constexpr (EPI == 1 || EPI == 5) Ab = A + (size_t)g0 * (size_t)K;
  else Ab = A;
  const short* Wb = Wt + (size_t)z * (size_t)N * (size_t)K;

  const int tid = threadIdx.x;
  const int lane = tid & 63, wid = tid >> 6;
  const int srow = lane >> 2;            // 0..15 rows within a 16-row segment
  const int skc = (lane & 3) * 8;        // k chunk (8 bf16 = 16 B)

  int ar0 = m0 + wid * 32 + srow;
  int ar1 = ar0 + 16;
  if (ar0 > Mg - 1) ar0 = Mg - 1;
  if (ar1 > Mg - 1) ar1 = Mg - 1;
  if constexpr (EPI == 3){
    if (operm){ ar0 = operm[ar0]; ar1 = operm[ar1]; }
  }
  const short* ga0 = Ab + (size_t)ar0 * K + skc;
  const short* ga1 = Ab + (size_t)ar1 * K + skc;
  const int brow = n0 + wid * 32 + srow;
  const short* gb0 = Wb + (size_t)brow * K + skc;
  const short* gb1 = gb0 + (size_t)16 * K;

  const int wm = (wid >> 1) * 64, wn = (wid & 1) * 64;
  const int r16 = lane & 15, kb = lane >> 4;

  f32x4 acc[4][4];
#pragma unroll
  for (int a = 0; a < 4; a++)
#pragma unroll
    for (int b = 0; b < 4; b++) acc[a][b] = (f32x4){0.f, 0.f, 0.f, 0.f};

  const int NT = K / BK;
  int buf = 0;

  // prologue: stage tile 0
  {
    short* dA = &lds[0][0] + wid * 1024;
    short* dB = &lds[0][4096] + wid * 1024;
    GLL(ga0, dA); GLL(ga1, dA + 512);
    GLL(gb0, dB); GLL(gb1, dB + 512);
  }
  __syncthreads();

  for (int t = 0; t < NT; ++t){
    if (t + 1 < NT){
      const int kof = (t + 1) * BK;
      short* dA = &lds[buf ^ 1][0] + wid * 1024;
      short* dB = &lds[buf ^ 1][4096] + wid * 1024;
      GLL(ga0 + kof, dA); GLL(ga1 + kof, dA + 512);
      GLL(gb0 + kof, dB); GLL(gb1 + kof, dB + 512);
    }
    const short* sA = &lds[buf][0];
    const short* sB = &lds[buf][4096];
    short8 af[4], bfv[4];
#pragma unroll
    for (int mi = 0; mi < 4; mi++) af[mi] = *(const short8*)(sA + (wm + mi * 16 + r16) * 32 + kb * 8);
#pragma unroll
    for (int ni = 0; ni < 4; ni++) bfv[ni] = *(const short8*)(sB + (wn + ni * 16 + r16) * 32 + kb * 8);
#pragma unroll
    for (int mi = 0; mi < 4; mi++)
#pragma unroll
      for (int ni = 0; ni < 4; ni++)
        acc[mi][ni] = __builtin_amdgcn_mfma_f32_16x16x32_bf16(af[mi], bfv[ni], acc[mi][ni], 0, 0, 0);
    __syncthreads();
    buf ^= 1;
  }

#pragma unroll
  for (int mi = 0; mi < 4; mi++){
#pragma unroll
    for (int q = 0; q < 4; q++){
      const int i = m0 + wm + mi * 16 + kb * 4 + q;
      if (i >= Mg) continue;
#pragma unroll
      for (int ni = 0; ni < 4; ni++){
        const int n = n0 + wn + ni * 16 + r16;
        float v = acc[mi][ni][q] + bias[(size_t)z * bstride + n];
        if constexpr (EPI == 1){
          outb[((size_t)e * CB + (g0 + i)) * (size_t)N + n] = f2bs(v);
        } else if constexpr (EPI == 2){
          const int borig = operm[g0 + i];
          v += bs2f(res[(size_t)(g0 + i) * CD + n]);
          outb[((size_t)borig * CE + e) * (size_t)CO + n] = f2bs(v);
        } else if constexpr (EPI == 3){
          outb[(size_t)i * (size_t)N + n] = f2bs(v);
        } else if constexpr (EPI == 4){
          outf[(size_t)i * (size_t)N + n] = v;
        } else {
          outf[(size_t)(g0 + i) * (size_t)N + n] = fmaxf(v, 0.f);
        }
      }
    }
  }
}

// ---------- LN + relu over hact rows (in-place) ----------
__global__ __launch_bounds__(256) void k_ln(short* __restrict__ hact,
    const float* __restrict__ lng, const float* __restrict__ lnb, const int* __restrict__ meta){
  const int rowid = blockIdx.x;           // e*CB + i_sorted
  const int e = rowid >> 11, i = rowid & (CB - 1);
  const int r = (i >= meta[1]) + (i >= meta[2]) + (i >= meta[3]);
  short* p = hact + (size_t)rowid * CH;
  short8 raw = *(short8*)(p + threadIdx.x * 8);
  float v[8]; float s = 0.f, sq = 0.f;
#pragma unroll
  for (int j = 0; j < 8; j++){ v[j] = bs2f(raw[j]); s += v[j]; sq += v[j] * v[j]; }
  block_reduce2(s, sq);
  const float mean = s * (1.f / CH);
  const float var = sq * (1.f / CH) - mean * mean;
  const float rstd = rsqrtf(fmaxf(var, 0.f) + 1e-5f);
  const float* g = lng + ((size_t)r * CE + e) * CH;
  const float* bb = lnb + ((size_t)r * CE + e) * CH;
  short8 outv;
#pragma unroll
  for (int j = 0; j < 8; j++){
    const int h = threadIdx.x * 8 + j;
    const float val = (v[j] - mean) * rstd * g[h] + bb[h];
    outv[j] = f2bs(fmaxf(val, 0.f));
  }
  *(short8*)(p + threadIdx.x * 8) = outv;
}

// ---------- attention over expert axis (q only for the 2 selected experts) ----------
__global__ __launch_bounds__(128) void k_attn(const short* __restrict__ qb, const short* __restrict__ kv,
    const int* __restrict__ tki, short* __restrict__ av){
  const int b = blockIdx.x;
  const int j = threadIdx.x >> 6, d = threadIdx.x & 63;
  const short* q = qb + (size_t)(b * 2 + j) * CO;
  const short* base = kv + (size_t)b * CE * 1024;
#pragma unroll
  for (int h = 0; h < 8; h++){
    const float qv = bs2f(q[h * 64 + d]);
    float sc[8];
#pragma unroll
    for (int e = 0; e < 8; e++){
      float pp = qv * bs2f(base[(size_t)e * 1024 + h * 64 + d]);
#pragma unroll
      for (int off = 32; off; off >>= 1) pp += __shfl_xor(pp, off, 64);
      sc[e] = pp * 0.125f;   // 1/sqrt(DH=64)
    }
    float m = sc[0];
#pragma unroll
    for (int e = 1; e < 8; e++) m = fmaxf(m, sc[e]);
    float den = 0.f, avd = 0.f;
#pragma unroll
    for (int e = 0; e < 8; e++){
      const float pe = __expf(sc[e] - m);
      den += pe;
      avd += pe * bs2f(base[(size_t)e * 1024 + 512 + h * 64 + d]);
    }
    av[((size_t)b * 2 + j) * CO + h * 64 + d] = f2bs(avd / den);
  }
}

// ---------- final LN + top-k combine ----------
__global__ __launch_bounds__(256) void k_final(const short* __restrict__ eo,
    const float* __restrict__ proj, const int* __restrict__ tki, const float* __restrict__ tkw,
    const float* __restrict__ ang, const float* __restrict__ anb, float* __restrict__ out){
  const int b = blockIdx.x, t = threadIdx.x;
  float o0 = 0.f, o1 = 0.f;
#pragma unroll
  for (int j = 0; j < 2; j++){
    const int s = tki[b * 2 + j];
    const float w = tkw[b * 2 + j];
    const short* ep = eo + ((size_t)b * CE + s) * CO;
    const float* pp = proj + ((size_t)b * 2 + j) * CO;
    const float v0 = bs2f(ep[t]) + pp[t];
    const float v1 = bs2f(ep[t + 256]) + pp[t + 256];
    float sm = v0 + v1, sq = v0 * v0 + v1 * v1;
    block_reduce2(sm, sq);
    const float mean = sm * (1.f / CO);
    const float rstd = rsqrtf(fmaxf(sq * (1.f / CO) - mean * mean, 0.f) + 1e-5f);
    o0 += w * ((v0 - mean) * rstd * ang[t] + anb[t]);
    o1 += w * ((v1 - mean) * rstd * ang[t + 256] + anb[t + 256]);
  }
  out[(size_t)b * CO + t] = o0;
  out[(size_t)b * CO + t + 256] = o1;
}

// ---------- launch ----------
extern "C" void kernel_launch(void* const* d_in, const int* in_sizes, int n_in,
                              void* d_out, int out_size, void* d_ws, size_t ws_size,
                              hipStream_t stream){
  const float* x    = (const float*)d_in[0];
  const int*   regime = (const int*)d_in[1];
  const float* ew1  = (const float*)d_in[3];
  const float* eb1  = (const float*)d_in[4];
  const float* lng  = (const float*)d_in[5];
  const float* lnb  = (const float*)d_in[6];
  const float* ew2  = (const float*)d_in[7];
  const float* eb2  = (const float*)d_in[8];
  const float* rw1  = (const float*)d_in[9];
  const float* rb1  = (const float*)d_in[10];
  const float* rw2  = (const float*)d_in[11];
  const float* rb2  = (const float*)d_in[12];
  const float* ipw  = (const float*)d_in[13];
  const float* ipb  = (const float*)d_in[14];
  const float* opw  = (const float*)d_in[15];
  const float* opb  = (const float*)d_in[16];
  const float* ang  = (const float*)d_in[17];
  const float* anb  = (const float*)d_in[18];
  float* out = (float*)d_out;

  char* ws = (char*)d_ws;
  // workspace layout (max ~167 MB, same footprint as round 2):
  int*   meta  = (int*)(ws);
  int*   perm  = (int*)(ws + (16u << 10));
  int*   tki   = (int*)(ws + (32u << 10));
  float* tkw   = (float*)(ws + (64u << 10));
  int*   qrows = (int*)(ws + (96u << 10));
  float* rbias = (float*)(ws + (128u << 10));    // f32 [4][2048] = 32 KB
  short* xp    = (short*)(ws + (1ull << 20));    // bf16 [2048][512] sorted = 2 MB
  short* ipwb  = (short*)(ws + (3ull << 20));    // bf16 [1536][512] = 1.5 MB
  short* opwb  = (short*)(ws + (5ull << 20));    // bf16 [512][512] = 0.5 MB
  float* rh    = (float*)(ws + (6ull << 20));    // f32 [2048][2048] = 16 MB (dead after k_logits)
  short* qb    = (short*)(ws + (6ull << 20));    // bf16 [4096][512] = 4 MB (overlays rh)
  float* proj  = (float*)(ws + (10ull << 20));   // f32 [4096][512] = 8 MB (overlays rh)
  short* av    = (short*)(ws + (18ull << 20));   // bf16 [4096][512] = 4 MB (overlays rh)
  short* hact  = (short*)(ws + (22ull << 20));   // bf16 [8][2048][2048] = 64 MB
  short* qkv   = hact;                           // bf16 [16384][1024] = 32 MB (hact dead)
  short* wt    = (short*)(ws + (86ull << 20));   // bf16 64 MiB: router B' (34 MB), then ew1t, then ew2t
  short* eo    = (short*)(ws + (150ull << 20));  // bf16 [2048][8][512] = 16 MB
  short* xd    = (short*)(ws + (150ull << 20));  // bf16 [2048][2048] = 8 MB (dead before eo written)

  hipMemsetAsync(meta, 0, 1024, stream);
  k_count  <<<8, 256, 0, stream>>>(regime, meta);
  k_scan   <<<1, 64, 0, stream>>>(meta);
  k_scatter<<<8, 256, 0, stream>>>(regime, meta, perm);
  k_xsplit <<<CB, 256, 0, stream>>>(x, perm, xp, xd);
  k_cvt    <<<384, 256, 0, stream>>>(ipw, ipwb, 1536 * 512);
  k_cvt    <<<128, 256, 0, stream>>>(opw, opwb, 512 * 512);

  // router: split-bf16 MFMA grouped GEMM (K'=2048 = [hi|hi|lo|lo]x[Whi|Wlo|Whi|Wlo])
  k_rwt  <<<dim3(32, 8, CR), 256, 0, stream>>>(rw1, wt);
  k_rbias<<<dim3(8, CR), 256, 0, stream>>>(rw1, rb1, rbias);
  gemm_bf16<5><<<dim3(16, 16, CR), 256, 0, stream>>>(
      xd, wt, meta, 0, 2048, CH, rbias, CH, nullptr, rh, nullptr, nullptr);
  k_logits<<<CB / 4, 256, 0, stream>>>(rh, rw2, rb2, meta, perm, tki, tkw);
  k_qrows<<<16, 256, 0, stream>>>(tki, qrows);

  // expert GEMM1: hact[e][i_sorted] = xp @ ew1t[r,e] + eb1
  k_cvt_t<<<dim3(32, 8, 32), 256, 0, stream>>>(ew1, wt, CD, CH);
  gemm_bf16<1><<<dim3(16, 16, CR * CE), 256, 0, stream>>>(
      xp, wt, meta, 0, CD, CH, eb1, CH, hact, nullptr, nullptr, nullptr);
  k_ln<<<CE * CB, 256, 0, stream>>>(hact, lng, lnb, meta);

  // expert GEMM2: eo[borig][e] = hact @ ew2t[r,e] + eb2 + xp
  k_cvt_t<<<dim3(8, 32, 32), 256, 0, stream>>>(ew2, wt, CH, CO);
  gemm_bf16<2><<<dim3(4, 16, CR * CE), 256, 0, stream>>>(
      hact, wt, meta, 0, CH, CO, eb2, CO, eo, nullptr, xp, perm);

  // KV for all (b,e): qkv[row][1024] = eo @ ipwb[512:1536] + ipb[512:]
  gemm_bf16<3><<<dim3(8, 128, 1), 256, 0, stream>>>(
      eo, ipwb + (size_t)512 * 512, nullptr, CB * CE, CO, 1024, ipb + 512, 0, qkv, nullptr, nullptr, nullptr);
  // Q only for selected experts: qb[b*2+j] = eo[qrows] @ ipwb[0:512] + ipb[:512]
  gemm_bf16<3><<<dim3(4, 32, 1), 256, 0, stream>>>(
      eo, ipwb, nullptr, CB * 2, CO, CO, ipb, 0, qb, nullptr, nullptr, qrows);

  k_attn<<<CB, 128, 0, stream>>>(qb, qkv, tki, av);

  // proj: proj[b*2+j] = av @ opwb + opb   (f32 out)
  gemm_bf16<4><<<dim3(4, 32, 1), 256, 0, stream>>>(
      av, opwb, nullptr, CB * 2, CO, CO, opb, 0, nullptr, proj, nullptr, nullptr);

  k_final<<<CB, 256, 0, stream>>>(eo, proj, tki, tkw, ang, anb, out);
  (void)in_sizes; (void)n_in; (void)out_size; (void)ws_size;
}

// Round 4
// 487.270 us; speedup vs baseline: 1.1655x; 1.0233x over previous
//
#include <hip/hip_runtime.h>
#include <hip/hip_bf16.h>
#include <cstddef>

typedef __attribute__((ext_vector_type(8))) short short8;
typedef __attribute__((ext_vector_type(4))) float f32x4;

constexpr int CB = 2048;   // batch
constexpr int CD = 512;    // input dim
constexpr int CH = 2048;   // expert hidden
constexpr int CO = 512;    // output dim
constexpr int CE = 8;      // experts
constexpr int CR = 4;      // regimes

// ---------- helpers ----------
__device__ __forceinline__ float bs2f(short s){
  union { float f; unsigned u; } u; u.u = ((unsigned)(unsigned short)s) << 16; return u.f;
}
__device__ __forceinline__ short f2bs(float x){
  union { __hip_bfloat16 h; short s; } u; u.h = __float2bfloat16(x); return u.s;
}

#define GLL(g, l) __builtin_amdgcn_global_load_lds((const __attribute__((address_space(1))) void*)(g), (__attribute__((address_space(3))) void*)(l), 16, 0, 0)

__device__ __forceinline__ void block_reduce2(float& a, float& b){
#pragma unroll
  for (int off = 32; off; off >>= 1){ a += __shfl_xor(a, off, 64); b += __shfl_xor(b, off, 64); }
  __shared__ float sa[4], sb[4];
  const int wid = threadIdx.x >> 6, lane = threadIdx.x & 63;
  __syncthreads();
  if (lane == 0){ sa[wid] = a; sb[wid] = b; }
  __syncthreads();
  a = sa[0] + sa[1] + sa[2] + sa[3];
  b = sb[0] + sb[1] + sb[2] + sb[3];
}

// ---------- regime bucketing ----------
__global__ void k_count(const int* __restrict__ regime, int* __restrict__ meta){
  int b = blockIdx.x * 256 + threadIdx.x;
  if (b < CB) atomicAdd(&meta[8 + regime[b]], 1);
}
__global__ void k_scan(int* meta){
  if (threadIdx.x == 0){
    int c0 = meta[8], c1 = meta[9], c2 = meta[10], c3 = meta[11];
    meta[0] = 0; meta[1] = c0; meta[2] = c0 + c1; meta[3] = c0 + c1 + c2; meta[4] = c0 + c1 + c2 + c3;
  }
}
__global__ void k_scatter(const int* __restrict__ regime, int* __restrict__ meta, int* __restrict__ perm){
  int b = blockIdx.x * 256 + threadIdx.x;
  if (b < CB){
    int r = regime[b];
    int pos = atomicAdd(&meta[12 + r], 1);
    perm[meta[r] + pos] = b;
  }
}

// gather x rows into sorted order; write bf16 hi (xp) and duplicated hi/lo router A' (xd)
__global__ __launch_bounds__(256) void k_xsplit(const float* __restrict__ x, const int* __restrict__ perm,
                                                short* __restrict__ xp, short* __restrict__ xd){
  const int i = blockIdx.x;
  const int b = perm[i];
  const int c = threadIdx.x * 2;
  float2 v = *(const float2*)(x + (size_t)b * CD + c);
  short2 hi; hi.x = f2bs(v.x); hi.y = f2bs(v.y);
  short2 lo; lo.x = f2bs(v.x - bs2f(hi.x)); lo.y = f2bs(v.y - bs2f(hi.y));
  *(short2*)(xp + (size_t)i * CD + c) = hi;
  short* row = xd + (size_t)i * 2048;
  *(short2*)(row + c) = hi;
  *(short2*)(row + 512 + c) = hi;
  *(short2*)(row + 1024 + c) = lo;
  *(short2*)(row + 1536 + c) = lo;
}

// plain f32 -> bf16 convert (layout preserved)
__global__ __launch_bounds__(256) void k_cvt(const float* __restrict__ in, short* __restrict__ outp, int n){
  int i = (blockIdx.x * 256 + threadIdx.x) * 8;
  if (i >= n) return;
  float4 a = *(const float4*)(in + i);
  float4 b = *(const float4*)(in + i + 4);
  short8 o;
  o[0]=f2bs(a.x); o[1]=f2bs(a.y); o[2]=f2bs(a.z); o[3]=f2bs(a.w);
  o[4]=f2bs(b.x); o[5]=f2bs(b.y); o[6]=f2bs(b.z); o[7]=f2bs(b.w);
  *(short8*)(outp + i) = o;
}

// f32 [K][N] -> bf16 [N][K] transpose+convert, per z matrix
__global__ __launch_bounds__(256) void k_cvt_t(const float* __restrict__ in, short* __restrict__ outp, int K, int N){
  __shared__ float tile[64][65];
  const int z = blockIdx.z;
  const int k0 = blockIdx.y * 64, n0 = blockIdx.x * 64;
  const float* src = in + (size_t)z * K * N;
  short* dst = outp + (size_t)z * K * N;
  const int t = threadIdx.x;
  const int kk = t >> 4, nq = (t & 15) * 4;
#pragma unroll
  for (int j = 0; j < 4; j++){
    float4 v = *(const float4*)(src + (size_t)(k0 + kk + j * 16) * N + n0 + nq);
    tile[kk + j * 16][nq] = v.x; tile[kk + j * 16][nq + 1] = v.y;
    tile[kk + j * 16][nq + 2] = v.z; tile[kk + j * 16][nq + 3] = v.w;
  }
  __syncthreads();
  const int n = t >> 2, kq = (t & 3) * 16;
  short8 o0, o1;
#pragma unroll
  for (int j = 0; j < 8; j++) o0[j] = f2bs(tile[kq + j][n]);
#pragma unroll
  for (int j = 0; j < 8; j++) o1[j] = f2bs(tile[kq + 8 + j][n]);
  short* drow = dst + (size_t)(n0 + n) * K + k0 + kq;
  *(short8*)(drow) = o0;
  *(short8*)(drow + 8) = o1;
}

// rw1 [r][512..][2048] f32 -> router B' [r][n][2048] bf16 = [Whi | Wlo | Whi | Wlo]
__global__ __launch_bounds__(256) void k_rwt(const float* __restrict__ rw1, short* __restrict__ Bp){
  __shared__ float tile[64][65];
  const int r = blockIdx.z;
  const int k0 = blockIdx.y * 64, n0 = blockIdx.x * 64;
  const float* src = rw1 + (size_t)r * (CD + CR) * CH;
  short* dst = Bp + (size_t)r * CH * 2048;
  const int t = threadIdx.x;
  const int kk = t >> 4, nq = (t & 15) * 4;
#pragma unroll
  for (int j = 0; j < 4; j++){
    float4 v = *(const float4*)(src + (size_t)(k0 + kk + j * 16) * CH + n0 + nq);
    tile[kk + j * 16][nq] = v.x; tile[kk + j * 16][nq + 1] = v.y;
    tile[kk + j * 16][nq + 2] = v.z; tile[kk + j * 16][nq + 3] = v.w;
  }
  __syncthreads();
  const int n = t >> 2, kq = (t & 3) * 16;
  short8 h0, h1, l0, l1;
#pragma unroll
  for (int j = 0; j < 8; j++){
    float f = tile[kq + j][n];
    short h = f2bs(f); h0[j] = h; l0[j] = f2bs(f - bs2f(h));
  }
#pragma unroll
  for (int j = 0; j < 8; j++){
    float f = tile[kq + 8 + j][n];
    short h = f2bs(f); h1[j] = h; l1[j] = f2bs(f - bs2f(h));
  }
  short* drow = dst + (size_t)(n0 + n) * 2048;
  *(short8*)(drow + k0 + kq) = h0;        *(short8*)(drow + k0 + kq + 8) = h1;
  *(short8*)(drow + 512 + k0 + kq) = l0;  *(short8*)(drow + 512 + k0 + kq + 8) = l1;
  *(short8*)(drow + 1024 + k0 + kq) = h0; *(short8*)(drow + 1024 + k0 + kq + 8) = h1;
  *(short8*)(drow + 1536 + k0 + kq) = l0; *(short8*)(drow + 1536 + k0 + kq + 8) = l1;
}

// rbias[r][n] = rb1[r][n] + rw1[r][512+r][n]   (one-hot row folded in, f32)
__global__ void k_rbias(const float* __restrict__ rw1, const float* __restrict__ rb1, float* __restrict__ rbias){
  const int r = blockIdx.y, n = blockIdx.x * 256 + threadIdx.x;
  rbias[r * CH + n] = rb1[(size_t)r * CH + n] + rw1[((size_t)r * (CD + CR) + CD + r) * CH + n];
}

// ---------- logits + softmax + top-2 (f32, sums the 2 K-split router partials) ----------
__global__ __launch_bounds__(256) void k_logits(
    const float* __restrict__ rh, long pstr, const float* __restrict__ rbias,
    const float* __restrict__ rw2, const float* __restrict__ rb2,
    const int* __restrict__ meta, const int* __restrict__ perm,
    int* __restrict__ tki, float* __restrict__ tkw){
  const int wid = threadIdx.x >> 6, lane = threadIdx.x & 63;
  const int i = blockIdx.x * 4 + wid;
  const int r = (i >= meta[1]) + (i >= meta[2]) + (i >= meta[3]);
  const float* w2 = rw2 + (size_t)r * CH * CE;
  const float* row0 = rh + (size_t)i * CH;
  const float* row1 = row0 + pstr;
  const float* rb = rbias + (size_t)r * CH;
  float acc[CE];
#pragma unroll
  for (int e = 0; e < CE; e++) acc[e] = 0.f;
  for (int h = lane; h < CH; h += 64){
    const float rv = fmaxf(row0[h] + row1[h] + rb[h], 0.f);
    const float* wp = w2 + (size_t)h * CE;
#pragma unroll
    for (int e = 0; e < CE; e++) acc[e] += rv * wp[e];
  }
#pragma unroll
  for (int e = 0; e < CE; e++){
#pragma unroll
    for (int off = 32; off; off >>= 1) acc[e] += __shfl_xor(acc[e], off, 64);
    acc[e] += rb2[r * CE + e];
  }
  if (lane == 0){
    int i1 = 0; float m1 = acc[0];
#pragma unroll
    for (int e = 1; e < CE; e++) if (acc[e] > m1){ m1 = acc[e]; i1 = e; }
    int i2 = -1; float m2 = -1e30f;
#pragma unroll
    for (int e = 0; e < CE; e++) if (e != i1 && acc[e] > m2){ m2 = acc[e]; i2 = e; }
    const float e2 = __expf(m2 - m1);
    const float w1 = 1.f / (1.f + e2);
    const int b = perm[i];
    tki[b * 2] = i1; tki[b * 2 + 1] = i2;
    tkw[b * 2] = w1; tkw[b * 2 + 1] = e2 * w1;
  }
}
__global__ void k_qrows(const int* __restrict__ tki, int* __restrict__ qrows){
  int i = blockIdx.x * 256 + threadIdx.x;
  if (i < CB * 2) qrows[i] = (i >> 1) * CE + tki[i];
}

// ---------- bf16 MFMA GEMM, 128x128 tile, BK=32, global_load_lds, 2-phase dbuf ----------
// LDS fragment reads are bank-conflict-free via chunk-XOR swizzle applied to the
// per-lane GLOBAL source (rule #21: linear GLL dest + pre-swizzled source + swizzled read).
// B is bf16 [z][N][ldw] rows. A is bf16 [.][lda].
// EPI: 1 = expert GEMM1 (+bias -> outb, sorted rows; group r = z>>3)
//      2 = expert GEMM2 K-split partial (raw acc, scatter via operm -> outb/outb2 by ks)
//      3 = plain bf16 out (+bias); optional A row-gather via operm
//      4 = plain f32 out (+bias)
//      5 = router K-split partial (raw acc -> outf + ks*bstride; group r = z)
template<int EPI>
__global__ __launch_bounds__(256) void gemm_bf16(
    const short* __restrict__ A, long lda,
    const short* __restrict__ Wt, long ldw,
    const int* __restrict__ goff, int fixedM, int Ksub, int ksplit, int N,
    const float* __restrict__ bias, long bstride,
    short* __restrict__ outb, short* __restrict__ outb2, float* __restrict__ outf,
    const int* __restrict__ operm){
  constexpr int BK = 32;
  __shared__ __align__(16) short lds[2][8192];   // per buf: A 4096 | B 4096 shorts (32 KB total)

  const int zz = blockIdx.z;
  const int ks = zz % ksplit;
  const int z = zz / ksplit;
  int g0 = 0, Mg = fixedM;
  if (goff){ const int r = (EPI == 5) ? z : (z >> 3); g0 = goff[r]; Mg = goff[r + 1] - g0; }
  const int m0 = blockIdx.y * 128;
  if (m0 >= Mg) return;
  const int n0 = blockIdx.x * 128;
  const int e = z & 7;
  const long kbase = (long)ks * Ksub;

  const short* Ab;
  if constexpr (EPI == 2) Ab = A + ((size_t)e * CB + g0) * (size_t)lda;
  else if constexpr (EPI == 1 || EPI == 5) Ab = A + (size_t)g0 * (size_t)lda;
  else Ab = A;
  const short* Wb = Wt + (size_t)z * (size_t)N * (size_t)ldw;

  const int tid = threadIdx.x;
  const int lane = tid & 63, wid = tid >> 6;
  const int srow = lane >> 2;                         // 0..15 row within 16-row segment
  const int sc = (((lane & 3) ^ ((srow >> 1) & 3)) << 3);  // swizzled source k-chunk (shorts)

  int ar0 = m0 + wid * 32 + srow;
  int ar1 = ar0 + 16;
  if (ar0 > Mg - 1) ar0 = Mg - 1;
  if (ar1 > Mg - 1) ar1 = Mg - 1;
  if constexpr (EPI == 3){
    if (operm){ ar0 = operm[ar0]; ar1 = operm[ar1]; }
  }
  const short* ga0 = Ab + (size_t)ar0 * lda + kbase + sc;
  const short* ga1 = Ab + (size_t)ar1 * lda + kbase + sc;
  const int brow = n0 + wid * 32 + srow;
  const short* gb0 = Wb + (size_t)brow * ldw + kbase + sc;
  const short* gb1 = gb0 + (size_t)16 * ldw;

  const int wm = (wid >> 1) * 64, wn = (wid & 1) * 64;
  const int r16 = lane & 15, kb = lane >> 4;
  const int rsw = (r16 >> 1) & 3;                     // read-side swizzle (lane-constant)

  f32x4 acc[4][4];
#pragma unroll
  for (int a = 0; a < 4; a++)
#pragma unroll
    for (int b = 0; b < 4; b++) acc[a][b] = (f32x4){0.f, 0.f, 0.f, 0.f};

  const int NT = Ksub / BK;
  int buf = 0;

  // prologue: stage tile 0
  {
    short* dA = &lds[0][0] + wid * 1024;
    short* dB = &lds[0][4096] + wid * 1024;
    GLL(ga0, dA); GLL(ga1, dA + 512);
    GLL(gb0, dB); GLL(gb1, dB + 512);
  }
  __syncthreads();

  for (int t = 0; t < NT; ++t){
    if (t + 1 < NT){
      const int kof = (t + 1) * BK;
      short* dA = &lds[buf ^ 1][0] + wid * 1024;
      short* dB = &lds[buf ^ 1][4096] + wid * 1024;
      GLL(ga0 + kof, dA); GLL(ga1 + kof, dA + 512);
      GLL(gb0 + kof, dB); GLL(gb1 + kof, dB + 512);
    }
    const short* sA = &lds[buf][0];
    const short* sB = &lds[buf][4096];
    short8 af[4], bfv[4];
#pragma unroll
    for (int mi = 0; mi < 4; mi++)
      af[mi] = *(const short8*)(sA + (wm + mi * 16 + r16) * 32 + ((kb ^ rsw) << 3));
#pragma unroll
    for (int ni = 0; ni < 4; ni++)
      bfv[ni] = *(const short8*)(sB + (wn + ni * 16 + r16) * 32 + ((kb ^ rsw) << 3));
#pragma unroll
    for (int mi = 0; mi < 4; mi++)
#pragma unroll
      for (int ni = 0; ni < 4; ni++)
        acc[mi][ni] = __builtin_amdgcn_mfma_f32_16x16x32_bf16(af[mi], bfv[ni], acc[mi][ni], 0, 0, 0);
    __syncthreads();
    buf ^= 1;
  }

#pragma unroll
  for (int mi = 0; mi < 4; mi++){
#pragma unroll
    for (int q = 0; q < 4; q++){
      const int i = m0 + wm + mi * 16 + kb * 4 + q;
      if (i >= Mg) continue;
#pragma unroll
      for (int ni = 0; ni < 4; ni++){
        const int n = n0 + wn + ni * 16 + r16;
        float v = acc[mi][ni][q];
        if constexpr (EPI == 1){
          v += bias[(size_t)z * bstride + n];
          outb[((size_t)e * CB + (g0 + i)) * (size_t)N + n] = f2bs(v);
        } else if constexpr (EPI == 2){
          const int borig = operm[g0 + i];
          short* tgt = ks ? outb2 : outb;
          tgt[((size_t)borig * CE + e) * (size_t)CO + n] = f2bs(v);
        } else if constexpr (EPI == 3){
          v += bias[n];
          outb[(size_t)i * (size_t)N + n] = f2bs(v);
        } else if constexpr (EPI == 4){
          v += bias[n];
          outf[(size_t)i * (size_t)N + n] = v;
        } else {
          outf[(size_t)(g0 + i) * (size_t)N + n + (size_t)ks * bstride] = v;
        }
      }
    }
  }
}

// ---------- combine GEMM2 K-split partials + bias + f32 residual -> eo bf16 (in-place on p0) ----------
__global__ __launch_bounds__(256) void k_eo(const short* __restrict__ p1,
    const float* __restrict__ eb2, const float* __restrict__ x, const int* __restrict__ regime,
    short* __restrict__ eo){
  const int b = blockIdx.x, e = blockIdx.y;
  const int r = regime[b];
  const int c = threadIdx.x * 2;
  const size_t idx = (((size_t)b * CE + e) << 9) + c;
  short2 a = *(const short2*)(eo + idx);
  short2 bb = *(const short2*)(p1 + idx);
  float2 xr = *(const float2*)(x + (size_t)b * CD + c);
  float2 eb = *(const float2*)(eb2 + (((size_t)r * CE + e) << 9) + c);
  short2 o;
  o.x = f2bs(bs2f(a.x) + bs2f(bb.x) + xr.x + eb.x);
  o.y = f2bs(bs2f(a.y) + bs2f(bb.y) + xr.y + eb.y);
  *(short2*)(eo + idx) = o;
}

// ---------- LN + relu over hact rows (in-place) ----------
__global__ __launch_bounds__(256) void k_ln(short* __restrict__ hact,
    const float* __restrict__ lng, const float* __restrict__ lnb, const int* __restrict__ meta){
  const int rowid = blockIdx.x;           // e*CB + i_sorted
  const int e = rowid >> 11, i = rowid & (CB - 1);
  const int r = (i >= meta[1]) + (i >= meta[2]) + (i >= meta[3]);
  short* p = hact + (size_t)rowid * CH;
  short8 raw = *(short8*)(p + threadIdx.x * 8);
  float v[8]; float s = 0.f, sq = 0.f;
#pragma unroll
  for (int j = 0; j < 8; j++){ v[j] = bs2f(raw[j]); s += v[j]; sq += v[j] * v[j]; }
  block_reduce2(s, sq);
  const float mean = s * (1.f / CH);
  const float var = sq * (1.f / CH) - mean * mean;
  const float rstd = rsqrtf(fmaxf(var, 0.f) + 1e-5f);
  const float* g = lng + ((size_t)r * CE + e) * CH;
  const float* bb = lnb + ((size_t)r * CE + e) * CH;
  short8 outv;
#pragma unroll
  for (int j = 0; j < 8; j++){
    const int h = threadIdx.x * 8 + j;
    const float val = (v[j] - mean) * rstd * g[h] + bb[h];
    outv[j] = f2bs(fmaxf(val, 0.f));
  }
  *(short8*)(p + threadIdx.x * 8) = outv;
}

// ---------- attention over expert axis (q only for the 2 selected experts) ----------
__global__ __launch_bounds__(128) void k_attn(const short* __restrict__ qb, const short* __restrict__ kv,
    const int* __restrict__ tki, short* __restrict__ av){
  const int b = blockIdx.x;
  const int j = threadIdx.x >> 6, d = threadIdx.x & 63;
  const short* q = qb + (size_t)(b * 2 + j) * CO;
  const short* base = kv + (size_t)b * CE * 1024;
#pragma unroll
  for (int h = 0; h < 8; h++){
    const float qv = bs2f(q[h * 64 + d]);
    float sc[8];
#pragma unroll
    for (int e = 0; e < 8; e++){
      float pp = qv * bs2f(base[(size_t)e * 1024 + h * 64 + d]);
#pragma unroll
      for (int off = 32; off; off >>= 1) pp += __shfl_xor(pp, off, 64);
      sc[e] = pp * 0.125f;   // 1/sqrt(DH=64)
    }
    float m = sc[0];
#pragma unroll
    for (int e = 1; e < 8; e++) m = fmaxf(m, sc[e]);
    float den = 0.f, avd = 0.f;
#pragma unroll
    for (int e = 0; e < 8; e++){
      const float pe = __expf(sc[e] - m);
      den += pe;
      avd += pe * bs2f(base[(size_t)e * 1024 + 512 + h * 64 + d]);
    }
    av[((size_t)b * 2 + j) * CO + h * 64 + d] = f2bs(avd / den);
  }
}

// ---------- final LN + top-k combine ----------
__global__ __launch_bounds__(256) void k_final(const short* __restrict__ eo,
    const float* __restrict__ proj, const int* __restrict__ tki, const float* __restrict__ tkw,
    const float* __restrict__ ang, const float* __restrict__ anb, float* __restrict__ out){
  const int b = blockIdx.x, t = threadIdx.x;
  float o0 = 0.f, o1 = 0.f;
#pragma unroll
  for (int j = 0; j < 2; j++){
    const int s = tki[b * 2 + j];
    const float w = tkw[b * 2 + j];
    const short* ep = eo + ((size_t)b * CE + s) * CO;
    const float* pp = proj + ((size_t)b * 2 + j) * CO;
    const float v0 = bs2f(ep[t]) + pp[t];
    const float v1 = bs2f(ep[t + 256]) + pp[t + 256];
    float sm = v0 + v1, sq = v0 * v0 + v1 * v1;
    block_reduce2(sm, sq);
    const float mean = sm * (1.f / CO);
    const float rstd = rsqrtf(fmaxf(sq * (1.f / CO) - mean * mean, 0.f) + 1e-5f);
    o0 += w * ((v0 - mean) * rstd * ang[t] + anb[t]);
    o1 += w * ((v1 - mean) * rstd * ang[t + 256] + anb[t + 256]);
  }
  out[(size_t)b * CO + t] = o0;
  out[(size_t)b * CO + t + 256] = o1;
}

// ---------- launch ----------
extern "C" void kernel_launch(void* const* d_in, const int* in_sizes, int n_in,
                              void* d_out, int out_size, void* d_ws, size_t ws_size,
                              hipStream_t stream){
  const float* x    = (const float*)d_in[0];
  const int*   regime = (const int*)d_in[1];
  const float* ew1  = (const float*)d_in[3];
  const float* eb1  = (const float*)d_in[4];
  const float* lng  = (const float*)d_in[5];
  const float* lnb  = (const float*)d_in[6];
  const float* ew2  = (const float*)d_in[7];
  const float* eb2  = (const float*)d_in[8];
  const float* rw1  = (const float*)d_in[9];
  const float* rb1  = (const float*)d_in[10];
  const float* rw2  = (const float*)d_in[11];
  const float* rb2  = (const float*)d_in[12];
  const float* ipw  = (const float*)d_in[13];
  const float* ipb  = (const float*)d_in[14];
  const float* opw  = (const float*)d_in[15];
  const float* opb  = (const float*)d_in[16];
  const float* ang  = (const float*)d_in[17];
  const float* anb  = (const float*)d_in[18];
  float* out = (float*)d_out;

  char* ws = (char*)d_ws;
  // workspace layout (<= 166 MiB, all overlays time-disjoint):
  int*   meta  = (int*)(ws);                        //  @0, 1 KB
  int*   perm  = (int*)(ws + (16u << 10));
  int*   tki   = (int*)(ws + (32u << 10));
  float* tkw   = (float*)(ws + (48u << 10));
  int*   qrows = (int*)(ws + (64u << 10));
  float* rbias = (float*)(ws + (80u << 10));        //  32 KB
  short* ipwb  = (short*)(ws + (256u << 10));       //  @0.25 MiB, 1.5 MiB
  short* opwb  = (short*)(ws + (1792u << 10));      //  @1.75, 0.5 MiB
  short* xp    = (short*)(ws + (2304u << 10));      //  @2.25, 2 MiB
  short* eo    = (short*)(ws + (4352u << 10));      //  @4.25, 16 MiB  (= GEMM2 partial p0, then final eo)
  float* rh    = (float*)(ws + (20736ull << 10));   //  @20.25, 16 MiB f32 (router partial 0; dead after k_logits)
  short* hact  = (short*)(ws + (22ull << 20));      //  @22, 64 MiB  (written by GEMM1, after rh dead)
  short* qkv   = (short*)(ws + (22ull << 20));      //  @22, 32 MiB  (after hact dead)
  short* qb    = (short*)(ws + (54ull << 20));      //  @54, 4 MiB
  short* av    = (short*)(ws + (58ull << 20));      //  @58, 4 MiB
  float* proj  = (float*)(ws + (62ull << 20));      //  @62, 8 MiB
  short* wt    = (short*)(ws + (86ull << 20));      //  @86, 64 MiB (router B' 32, then ew1t, then ew2t)
  short* xd    = (short*)(ws + (118ull << 20));     //  @118, 16 MiB (router A'; dead after router gemm)
  float* rh1   = (float*)(ws + (134ull << 20));     //  @134, 16 MiB (router partial 1)
  short* p1    = (short*)(ws + (150ull << 20));     //  @150, 16 MiB (GEMM2 partial 1)
  const long RHPS = (long)(rh1 - rh);               // element offset between router partials

  hipMemsetAsync(meta, 0, 1024, stream);
  k_count  <<<8, 256, 0, stream>>>(regime, meta);
  k_scan   <<<1, 64, 0, stream>>>(meta);
  k_scatter<<<8, 256, 0, stream>>>(regime, meta, perm);
  k_xsplit <<<CB, 256, 0, stream>>>(x, perm, xp, xd);
  k_cvt    <<<384, 256, 0, stream>>>(ipw, ipwb, 1536 * 512);
  k_cvt    <<<128, 256, 0, stream>>>(opw, opwb, 512 * 512);

  // router: split-bf16 MFMA grouped GEMM (K'=2048 = [hi|hi|lo|lo]x[Whi|Wlo|Whi|Wlo]), K-split x2
  k_rwt  <<<dim3(32, 8, CR), 256, 0, stream>>>(rw1, wt);
  k_rbias<<<dim3(8, CR), 256, 0, stream>>>(rw1, rb1, rbias);
  gemm_bf16<5><<<dim3(16, 16, CR * 2), 256, 0, stream>>>(
      xd, 2048, wt, 2048, meta, 0, 1024, 2, CH, nullptr, RHPS, nullptr, nullptr, rh, nullptr);
  k_logits<<<CB / 4, 256, 0, stream>>>(rh, RHPS, rbias, rw2, rb2, meta, perm, tki, tkw);
  k_qrows<<<16, 256, 0, stream>>>(tki, qrows);

  // expert GEMM1: hact[e][i_sorted] = xp @ ew1t[r,e] + eb1
  k_cvt_t<<<dim3(32, 8, 32), 256, 0, stream>>>(ew1, wt, CD, CH);
  gemm_bf16<1><<<dim3(16, 16, CR * CE), 256, 0, stream>>>(
      xp, CD, wt, CD, meta, 0, CD, 1, CH, eb1, CH, hact, nullptr, nullptr, nullptr);
  k_ln<<<CE * CB, 256, 0, stream>>>(hact, lng, lnb, meta);

  // expert GEMM2 (K-split x2): partials -> eo(p0)/p1, scattered by borig
  k_cvt_t<<<dim3(8, 32, 32), 256, 0, stream>>>(ew2, wt, CH, CO);
  gemm_bf16<2><<<dim3(4, 16, CR * CE * 2), 256, 0, stream>>>(
      hact, CH, wt, CH, meta, 0, 1024, 2, CO, nullptr, 0, eo, p1, nullptr, perm);
  k_eo<<<dim3(CB, CE), 256, 0, stream>>>(p1, eb2, x, regime, eo);

  // KV for all (b,e): qkv[row][1024] = eo @ ipwb[512:1536] + ipb[512:]
  gemm_bf16<3><<<dim3(8, 128, 1), 256, 0, stream>>>(
      eo, CO, ipwb + (size_t)512 * 512, CO, nullptr, CB * CE, CO, 1, 1024, ipb + 512, 0, qkv, nullptr, nullptr, nullptr);
  // Q only for selected experts: qb[b*2+j] = eo[qrows] @ ipwb[0:512] + ipb[:512]
  gemm_bf16<3><<<dim3(4, 32, 1), 256, 0, stream>>>(
      eo, CO, ipwb, CO, nullptr, CB * 2, CO, 1, CO, ipb, 0, qb, nullptr, nullptr, qrows);

  k_attn<<<CB, 128, 0, stream>>>(qb, qkv, tki, av);

  // proj: proj[b*2+j] = av @ opwb + opb   (f32 out)
  gemm_bf16<4><<<dim3(4, 32, 1), 256, 0, stream>>>(
      av, CO, opwb, CO, nullptr, CB * 2, CO, 1, CO, opb, 0, nullptr, nullptr, proj, nullptr);

  k_final<<<CB, 256, 0, stream>>>(eo, proj, tki, tkw, ang, anb, out);
  (void)in_sizes; (void)n_in; (void)out_size; (void)ws_size;
}

// Round 6
// 441.228 us; speedup vs baseline: 1.2871x; 1.1043x over previous
//
#include <hip/hip_runtime.h>
#include <hip/hip_bf16.h>
#include <cstddef>

typedef __attribute__((ext_vector_type(8))) short short8;
typedef __attribute__((ext_vector_type(4))) float f32x4;

constexpr int CB = 2048;   // batch
constexpr int CD = 512;    // input dim
constexpr int CH = 2048;   // expert hidden
constexpr int CO = 512;    // output dim
constexpr int CE = 8;      // experts
constexpr int CR = 4;      // regimes

// ---------- helpers ----------
__device__ __forceinline__ float bs2f(short s){
  union { float f; unsigned u; } u; u.u = ((unsigned)(unsigned short)s) << 16; return u.f;
}
__device__ __forceinline__ short f2bs(float x){
  union { __hip_bfloat16 h; short s; } u; u.h = __float2bfloat16(x); return u.s;
}

#define GLL(g, l) __builtin_amdgcn_global_load_lds((const __attribute__((address_space(1))) void*)(g), (__attribute__((address_space(3))) void*)(l), 16, 0, 0)

__device__ __forceinline__ void block_reduce2(float& a, float& b){
#pragma unroll
  for (int off = 32; off; off >>= 1){ a += __shfl_xor(a, off, 64); b += __shfl_xor(b, off, 64); }
  __shared__ float sa[4], sb[4];
  const int wid = threadIdx.x >> 6, lane = threadIdx.x & 63;
  __syncthreads();
  if (lane == 0){ sa[wid] = a; sb[wid] = b; }
  __syncthreads();
  a = sa[0] + sa[1] + sa[2] + sa[3];
  b = sb[0] + sb[1] + sb[2] + sb[3];
}

// ---------- regime bucketing ----------
__global__ void k_count(const int* __restrict__ regime, int* __restrict__ meta){
  int b = blockIdx.x * 256 + threadIdx.x;
  if (b < CB) atomicAdd(&meta[8 + regime[b]], 1);
}
__global__ void k_scan(int* meta){
  if (threadIdx.x == 0){
    int c0 = meta[8], c1 = meta[9], c2 = meta[10], c3 = meta[11];
    meta[0] = 0; meta[1] = c0; meta[2] = c0 + c1; meta[3] = c0 + c1 + c2; meta[4] = c0 + c1 + c2 + c3;
  }
}
__global__ void k_scatter(const int* __restrict__ regime, int* __restrict__ meta, int* __restrict__ perm){
  int b = blockIdx.x * 256 + threadIdx.x;
  if (b < CB){
    int r = regime[b];
    int pos = atomicAdd(&meta[12 + r], 1);
    perm[meta[r] + pos] = b;
  }
}

// gather x rows into sorted order; write bf16 hi (xp) and router A' = [hi|hi|lo|lo] (xd, K'=2048)
__global__ __launch_bounds__(256) void k_xsplit(const float* __restrict__ x, const int* __restrict__ perm,
                                                short* __restrict__ xp, short* __restrict__ xd){
  const int i = blockIdx.x;
  const int b = perm[i];
  const int c = threadIdx.x * 2;
  float2 v = *(const float2*)(x + (size_t)b * CD + c);
  short2 hi; hi.x = f2bs(v.x); hi.y = f2bs(v.y);
  short2 lo; lo.x = f2bs(v.x - bs2f(hi.x)); lo.y = f2bs(v.y - bs2f(hi.y));
  *(short2*)(xp + (size_t)i * CD + c) = hi;
  short* row = xd + (size_t)i * 2048;
  *(short2*)(row + c) = hi;
  *(short2*)(row + 512 + c) = hi;
  *(short2*)(row + 1024 + c) = lo;
  *(short2*)(row + 1536 + c) = lo;
}

// plain f32 -> bf16 convert (layout preserved)
__global__ __launch_bounds__(256) void k_cvt(const float* __restrict__ in, short* __restrict__ outp, int n){
  int i = (blockIdx.x * 256 + threadIdx.x) * 8;
  if (i >= n) return;
  float4 a = *(const float4*)(in + i);
  float4 b = *(const float4*)(in + i + 4);
  short8 o;
  o[0]=f2bs(a.x); o[1]=f2bs(a.y); o[2]=f2bs(a.z); o[3]=f2bs(a.w);
  o[4]=f2bs(b.x); o[5]=f2bs(b.y); o[6]=f2bs(b.z); o[7]=f2bs(b.w);
  *(short8*)(outp + i) = o;
}

// f32 [K][N] -> bf16 [N][K] transpose+convert, per z matrix
__global__ __launch_bounds__(256) void k_cvt_t(const float* __restrict__ in, short* __restrict__ outp, int K, int N){
  __shared__ float tile[64][65];
  const int z = blockIdx.z;
  const int k0 = blockIdx.y * 64, n0 = blockIdx.x * 64;
  const float* src = in + (size_t)z * K * N;
  short* dst = outp + (size_t)z * K * N;
  const int t = threadIdx.x;
  const int kk = t >> 4, nq = (t & 15) * 4;
#pragma unroll
  for (int j = 0; j < 4; j++){
    float4 v = *(const float4*)(src + (size_t)(k0 + kk + j * 16) * N + n0 + nq);
    tile[kk + j * 16][nq] = v.x; tile[kk + j * 16][nq + 1] = v.y;
    tile[kk + j * 16][nq + 2] = v.z; tile[kk + j * 16][nq + 3] = v.w;
  }
  __syncthreads();
  const int n = t >> 2, kq = (t & 3) * 16;
  short8 o0, o1;
#pragma unroll
  for (int j = 0; j < 8; j++) o0[j] = f2bs(tile[kq + j][n]);
#pragma unroll
  for (int j = 0; j < 8; j++) o1[j] = f2bs(tile[kq + 8 + j][n]);
  short* drow = dst + (size_t)(n0 + n) * K + k0 + kq;
  *(short8*)(drow) = o0;
  *(short8*)(drow + 8) = o1;
}

// rw1 [r][512..][2048] f32 -> router B' [r][n][2048] bf16 = [Whi | Wlo | Whi | Wlo]
__global__ __launch_bounds__(256) void k_rwt(const float* __restrict__ rw1, short* __restrict__ Bp){
  __shared__ float tile[64][65];
  const int r = blockIdx.z;
  const int k0 = blockIdx.y * 64, n0 = blockIdx.x * 64;
  const float* src = rw1 + (size_t)r * (CD + CR) * CH;
  short* dst = Bp + (size_t)r * CH * 2048;
  const int t = threadIdx.x;
  const int kk = t >> 4, nq = (t & 15) * 4;
#pragma unroll
  for (int j = 0; j < 4; j++){
    float4 v = *(const float4*)(src + (size_t)(k0 + kk + j * 16) * CH + n0 + nq);
    tile[kk + j * 16][nq] = v.x; tile[kk + j * 16][nq + 1] = v.y;
    tile[kk + j * 16][nq + 2] = v.z; tile[kk + j * 16][nq + 3] = v.w;
  }
  __syncthreads();
  const int n = t >> 2, kq = (t & 3) * 16;
  short8 h0, h1, l0, l1;
#pragma unroll
  for (int j = 0; j < 8; j++){
    float f = tile[kq + j][n];
    short h = f2bs(f); h0[j] = h; l0[j] = f2bs(f - bs2f(h));
  }
#pragma unroll
  for (int j = 0; j < 8; j++){
    float f = tile[kq + 8 + j][n];
    short h = f2bs(f); h1[j] = h; l1[j] = f2bs(f - bs2f(h));
  }
  short* drow = dst + (size_t)(n0 + n) * 2048;
  *(short8*)(drow + k0 + kq) = h0;        *(short8*)(drow + k0 + kq + 8) = h1;
  *(short8*)(drow + 512 + k0 + kq) = l0;  *(short8*)(drow + 512 + k0 + kq + 8) = l1;
  *(short8*)(drow + 1024 + k0 + kq) = h0; *(short8*)(drow + 1024 + k0 + kq + 8) = h1;
  *(short8*)(drow + 1536 + k0 + kq) = l0; *(short8*)(drow + 1536 + k0 + kq + 8) = l1;
}

// rbias[r][n] = rb1[r][n] + rw1[r][512+r][n]   (one-hot row folded in, f32)
__global__ void k_rbias(const float* __restrict__ rw1, const float* __restrict__ rb1, float* __restrict__ rbias){
  const int r = blockIdx.y, n = blockIdx.x * 256 + threadIdx.x;
  rbias[r * CH + n] = rb1[(size_t)r * CH + n] + rw1[((size_t)r * (CD + CR) + CD + r) * CH + n];
}

// ---------- reduce 32 logit partials + softmax + top-2 (f32, deterministic) ----------
__global__ __launch_bounds__(256) void k_logits2(
    const float* __restrict__ part, const float* __restrict__ rb2,
    const int* __restrict__ meta, const int* __restrict__ perm,
    int* __restrict__ tki, float* __restrict__ tkw){
  const int wid = threadIdx.x >> 6, lane = threadIdx.x & 63;
  const int i = blockIdx.x * 4 + wid;
  const int r = (i >= meta[1]) + (i >= meta[2]) + (i >= meta[3]);
  const int p0 = lane >> 3, e = lane & 7;
  float v = 0.f;
#pragma unroll
  for (int j = 0; j < 4; j++)
    v += part[((size_t)(p0 + 8 * j) * CB + i) * 8 + e];
  v += __shfl_xor(v, 8, 64);
  v += __shfl_xor(v, 16, 64);
  v += __shfl_xor(v, 32, 64);
  v += rb2[r * CE + e];
  // convergent broadcast (ALL lanes execute the shfl; selection then lane-private)
  float l8[8];
#pragma unroll
  for (int e2 = 0; e2 < 8; e2++) l8[e2] = __shfl(v, e2, 64);
  if (lane == 0){
    int i1 = 0; float m1 = l8[0];
#pragma unroll
    for (int e2 = 1; e2 < 8; e2++) if (l8[e2] > m1){ m1 = l8[e2]; i1 = e2; }
    int i2 = -1; float m2 = -1e30f;
#pragma unroll
    for (int e2 = 0; e2 < 8; e2++) if (e2 != i1 && l8[e2] > m2){ m2 = l8[e2]; i2 = e2; }
    const float e2w = __expf(m2 - m1);
    const float w1 = 1.f / (1.f + e2w);
    const int b = perm[i];
    tki[b * 2] = i1; tki[b * 2 + 1] = i2;
    tkw[b * 2] = w1; tkw[b * 2 + 1] = e2w * w1;
  }
}
__global__ void k_qrows(const int* __restrict__ tki, int* __restrict__ qrows){
  int i = blockIdx.x * 256 + threadIdx.x;
  if (i < CB * 2) qrows[i] = (i >> 1) * CE + tki[i];
}

// ---------- bf16 MFMA GEMM, 128x128 tile, BK=32, global_load_lds, 2-phase dbuf ----------
// LDS conflict-free: linear GLL dest + pre-swizzled global source + swizzled ds_read (rule #21).
// SWZ: 1-D grid with bijective XCD-chunk swizzle (all blocks of one z-group land on one XCD's L2).
// EPI: 1 = expert GEMM1 (+bias -> outb, sorted rows; group r = z>>3)
//      2 = expert GEMM2 K-split partial (raw acc, scatter via operm -> outb/outb2 by ks)
//      3 = plain bf16 out (+bias); optional A row-gather via operm
//      4 = plain f32 out (+bias)
//      6 = fused router: +rbias, relu, contract with rw2 (xtra) -> logit partials [32][CB][8] (outf)
template<int EPI, bool SWZ>
__global__ __launch_bounds__(256) void gemm_bf16(
    const short* __restrict__ A, long lda,
    const short* __restrict__ Wt, long ldw,
    const int* __restrict__ goff, int fixedM, int Ksub, int ksplit, int N,
    const float* __restrict__ bias, long bstride,
    short* __restrict__ outb, short* __restrict__ outb2, float* __restrict__ outf,
    const int* __restrict__ operm, const float* __restrict__ xtra, int mbs, int nbs){
  constexpr int BK = 32;
  __shared__ __align__(16) short lds[2][8192];   // per buf: A 4096 | B 4096 shorts (32 KB total)

  int bx, by, bz;
  if constexpr (SWZ){
    const int s = blockIdx.x;
    const int chunk = gridDim.x >> 3;            // gridDim.x % 8 == 0 (bijective)
    const int l = (s & 7) * chunk + (s >> 3);
    bx = l % nbs; const int t2 = l / nbs; by = t2 % mbs; bz = t2 / mbs;
  } else { bx = blockIdx.x; by = blockIdx.y; bz = blockIdx.z; }

  const int ks = bz % ksplit;
  const int z = bz / ksplit;
  int g0 = 0, Mg = fixedM;
  if (goff){ const int r = (EPI == 6) ? z : (z >> 3); g0 = goff[r]; Mg = goff[r + 1] - g0; }
  const int m0 = by * 128;
  if (m0 >= Mg) return;
  const int n0 = bx * 128;
  const int e = z & 7;
  const long kbase = (long)ks * Ksub;

  const short* Ab;
  if constexpr (EPI == 2) Ab = A + ((size_t)e * CB + g0) * (size_t)lda;
  else if constexpr (EPI == 1 || EPI == 6) Ab = A + (size_t)g0 * (size_t)lda;
  else Ab = A;
  const short* Wb = Wt + (size_t)z * (size_t)N * (size_t)ldw;

  const int tid = threadIdx.x;
  const int lane = tid & 63, wid = tid >> 6;
  const int srow = lane >> 2;                         // 0..15 row within 16-row segment
  const int sc = (((lane & 3) ^ ((srow >> 1) & 3)) << 3);  // swizzled source k-chunk (shorts)

  int ar0 = m0 + wid * 32 + srow;
  int ar1 = ar0 + 16;
  if (ar0 > Mg - 1) ar0 = Mg - 1;
  if (ar1 > Mg - 1) ar1 = Mg - 1;
  if constexpr (EPI == 3){
    if (operm){ ar0 = operm[ar0]; ar1 = operm[ar1]; }
  }
  const short* ga0 = Ab + (size_t)ar0 * lda + kbase + sc;
  const short* ga1 = Ab + (size_t)ar1 * lda + kbase + sc;
  const int brow = n0 + wid * 32 + srow;
  const short* gb0 = Wb + (size_t)brow * ldw + kbase + sc;
  const short* gb1 = gb0 + (size_t)16 * ldw;

  const int wm = (wid >> 1) * 64, wn = (wid & 1) * 64;
  const int r16 = lane & 15, kb = lane >> 4;
  const int rsw = (r16 >> 1) & 3;                     // read-side swizzle (lane-constant)

  f32x4 acc[4][4];
#pragma unroll
  for (int a = 0; a < 4; a++)
#pragma unroll
    for (int b = 0; b < 4; b++) acc[a][b] = (f32x4){0.f, 0.f, 0.f, 0.f};

  const int NT = Ksub / BK;
  int buf = 0;

  // prologue: stage tile 0
  {
    short* dA = &lds[0][0] + wid * 1024;
    short* dB = &lds[0][4096] + wid * 1024;
    GLL(ga0, dA); GLL(ga1, dA + 512);
    GLL(gb0, dB); GLL(gb1, dB + 512);
  }
  __syncthreads();

  for (int t = 0; t < NT; ++t){
    if (t + 1 < NT){
      const int kof = (t + 1) * BK;
      short* dA = &lds[buf ^ 1][0] + wid * 1024;
      short* dB = &lds[buf ^ 1][4096] + wid * 1024;
      GLL(ga0 + kof, dA); GLL(ga1 + kof, dA + 512);
      GLL(gb0 + kof, dB); GLL(gb1 + kof, dB + 512);
    }
    const short* sA = &lds[buf][0];
    const short* sB = &lds[buf][4096];
    short8 af[4], bfv[4];
#pragma unroll
    for (int mi = 0; mi < 4; mi++)
      af[mi] = *(const short8*)(sA + (wm + mi * 16 + r16) * 32 + ((kb ^ rsw) << 3));
#pragma unroll
    for (int ni = 0; ni < 4; ni++)
      bfv[ni] = *(const short8*)(sB + (wn + ni * 16 + r16) * 32 + ((kb ^ rsw) << 3));
#pragma unroll
    for (int mi = 0; mi < 4; mi++)
#pragma unroll
      for (int ni = 0; ni < 4; ni++)
        acc[mi][ni] = __builtin_amdgcn_mfma_f32_16x16x32_bf16(af[mi], bfv[ni], acc[mi][ni], 0, 0, 0);
    __syncthreads();
    buf ^= 1;
  }

  if constexpr (EPI == 6){
    // fused router epilogue: relu(acc + rbias) @ rw2[h][8] -> partials[slot][row][8]
    const int hbase = n0 + wn;
    float wv[4][8]; float rbv[4];
#pragma unroll
    for (int ni = 0; ni < 4; ni++){
      const int h = hbase + ni * 16 + r16;
      rbv[ni] = bias[(size_t)z * CH + h];
      const float* wp = xtra + ((size_t)z * CH + h) * 8;
#pragma unroll
      for (int e2 = 0; e2 < 8; e2++) wv[ni][e2] = wp[e2];
    }
    const int slot = bx * 2 + (wid & 1);
#pragma unroll
    for (int mi = 0; mi < 4; mi++){
#pragma unroll
      for (int q = 0; q < 4; q++){
        float tmp[8];
#pragma unroll
        for (int e2 = 0; e2 < 8; e2++) tmp[e2] = 0.f;
#pragma unroll
        for (int ni = 0; ni < 4; ni++){
          const float v = fmaxf(acc[mi][ni][q] + rbv[ni], 0.f);
#pragma unroll
          for (int e2 = 0; e2 < 8; e2++) tmp[e2] += v * wv[ni][e2];
        }
#pragma unroll
        for (int e2 = 0; e2 < 8; e2++){
          tmp[e2] += __shfl_xor(tmp[e2], 1, 64);
          tmp[e2] += __shfl_xor(tmp[e2], 2, 64);
          tmp[e2] += __shfl_xor(tmp[e2], 4, 64);
          tmp[e2] += __shfl_xor(tmp[e2], 8, 64);
        }
        const int row = wm + mi * 16 + kb * 4 + q;
        if (r16 == 0 && m0 + row < Mg){
          float* dp = outf + ((size_t)slot * CB + (g0 + m0 + row)) * 8;
#pragma unroll
          for (int e2 = 0; e2 < 8; e2++) dp[e2] = tmp[e2];
        }
      }
    }
    return;
  }

#pragma unroll
  for (int mi = 0; mi < 4; mi++){
#pragma unroll
    for (int q = 0; q < 4; q++){
      const int i = m0 + wm + mi * 16 + kb * 4 + q;
      if (i >= Mg) continue;
#pragma unroll
      for (int ni = 0; ni < 4; ni++){
        const int n = n0 + wn + ni * 16 + r16;
        float v = acc[mi][ni][q];
        if constexpr (EPI == 1){
          v += bias[(size_t)z * bstride + n];
          outb[((size_t)e * CB + (g0 + i)) * (size_t)N + n] = f2bs(v);
        } else if constexpr (EPI == 2){
          const int borig = operm[g0 + i];
          short* tgt = ks ? outb2 : outb;
          tgt[((size_t)borig * CE + e) * (size_t)CO + n] = f2bs(v);
        } else if constexpr (EPI == 3){
          v += bias[n];
          outb[(size_t)i * (size_t)N + n] = f2bs(v);
        } else {
          v += bias[n];
          outf[(size_t)i * (size_t)N + n] = v;
        }
      }
    }
  }
}

// ---------- combine GEMM2 K-split partials + bias + f32 residual -> eo bf16 (in-place on p0) ----------
__global__ __launch_bounds__(256) void k_eo(const short* __restrict__ p1,
    const float* __restrict__ eb2, const float* __restrict__ x, const int* __restrict__ regime,
    short* __restrict__ eo){
  const int b = blockIdx.x, e = blockIdx.y;
  const int r = regime[b];
  const int c = threadIdx.x * 2;
  const size_t idx = (((size_t)b * CE + e) << 9) + c;
  short2 a = *(const short2*)(eo + idx);
  short2 bb = *(const short2*)(p1 + idx);
  float2 xr = *(const float2*)(x + (size_t)b * CD + c);
  float2 eb = *(const float2*)(eb2 + (((size_t)r * CE + e) << 9) + c);
  short2 o;
  o.x = f2bs(bs2f(a.x) + bs2f(bb.x) + xr.x + eb.x);
  o.y = f2bs(bs2f(a.y) + bs2f(bb.y) + xr.y + eb.y);
  *(short2*)(eo + idx) = o;
}

// ---------- LN + relu over hact rows (in-place) ----------
__global__ __launch_bounds__(256) void k_ln(short* __restrict__ hact,
    const float* __restrict__ lng, const float* __restrict__ lnb, const int* __restrict__ meta){
  const int rowid = blockIdx.x;           // e*CB + i_sorted
  const int e = rowid >> 11, i = rowid & (CB - 1);
  const int r = (i >= meta[1]) + (i >= meta[2]) + (i >= meta[3]);
  short* p = hact + (size_t)rowid * CH;
  short8 raw = *(short8*)(p + threadIdx.x * 8);
  float v[8]; float s = 0.f, sq = 0.f;
#pragma unroll
  for (int j = 0; j < 8; j++){ v[j] = bs2f(raw[j]); s += v[j]; sq += v[j] * v[j]; }
  block_reduce2(s, sq);
  const float mean = s * (1.f / CH);
  const float var = sq * (1.f / CH) - mean * mean;
  const float rstd = rsqrtf(fmaxf(var, 0.f) + 1e-5f);
  const float* g = lng + ((size_t)r * CE + e) * CH;
  const float* bb = lnb + ((size_t)r * CE + e) * CH;
  short8 outv;
#pragma unroll
  for (int j = 0; j < 8; j++){
    const int h = threadIdx.x * 8 + j;
    const float val = (v[j] - mean) * rstd * g[h] + bb[h];
    outv[j] = f2bs(fmaxf(val, 0.f));
  }
  *(short8*)(p + threadIdx.x * 8) = outv;
}

// ---------- attention over expert axis (q only for the 2 selected experts) ----------
__global__ __launch_bounds__(128) void k_attn(const short* __restrict__ qb, const short* __restrict__ kv,
    const int* __restrict__ tki, short* __restrict__ av){
  const int b = blockIdx.x;
  const int j = threadIdx.x >> 6, d = threadIdx.x & 63;
  const short* q = qb + (size_t)(b * 2 + j) * CO;
  const short* base = kv + (size_t)b * CE * 1024;
#pragma unroll
  for (int h = 0; h < 8; h++){
    const float qv = bs2f(q[h * 64 + d]);
    float sc[8];
#pragma unroll
    for (int e = 0; e < 8; e++){
      float pp = qv * bs2f(base[(size_t)e * 1024 + h * 64 + d]);
#pragma unroll
      for (int off = 32; off; off >>= 1) pp += __shfl_xor(pp, off, 64);
      sc[e] = pp * 0.125f;   // 1/sqrt(DH=64)
    }
    float m = sc[0];
#pragma unroll
    for (int e = 1; e < 8; e++) m = fmaxf(m, sc[e]);
    float den = 0.f, avd = 0.f;
#pragma unroll
    for (int e = 0; e < 8; e++){
      const float pe = __expf(sc[e] - m);
      den += pe;
      avd += pe * bs2f(base[(size_t)e * 1024 + 512 + h * 64 + d]);
    }
    av[((size_t)b * 2 + j) * CO + h * 64 + d] = f2bs(avd / den);
  }
}

// ---------- final LN + top-k combine ----------
__global__ __launch_bounds__(256) void k_final(const short* __restrict__ eo,
    const float* __restrict__ proj, const int* __restrict__ tki, const float* __restrict__ tkw,
    const float* __restrict__ ang, const float* __restrict__ anb, float* __restrict__ out){
  const int b = blockIdx.x, t = threadIdx.x;
  float o0 = 0.f, o1 = 0.f;
#pragma unroll
  for (int j = 0; j < 2; j++){
    const int s = tki[b * 2 + j];
    const float w = tkw[b * 2 + j];
    const short* ep = eo + ((size_t)b * CE + s) * CO;
    const float* pp = proj + ((size_t)b * 2 + j) * CO;
    const float v0 = bs2f(ep[t]) + pp[t];
    const float v1 = bs2f(ep[t + 256]) + pp[t + 256];
    float sm = v0 + v1, sq = v0 * v0 + v1 * v1;
    block_reduce2(sm, sq);
    const float mean = sm * (1.f / CO);
    const float rstd = rsqrtf(fmaxf(sq * (1.f / CO) - mean * mean, 0.f) + 1e-5f);
    o0 += w * ((v0 - mean) * rstd * ang[t] + anb[t]);
    o1 += w * ((v1 - mean) * rstd * ang[t + 256] + anb[t + 256]);
  }
  out[(size_t)b * CO + t] = o0;
  out[(size_t)b * CO + t + 256] = o1;
}

// ---------- launch ----------
extern "C" void kernel_launch(void* const* d_in, const int* in_sizes, int n_in,
                              void* d_out, int out_size, void* d_ws, size_t ws_size,
                              hipStream_t stream){
  const float* x    = (const float*)d_in[0];
  const int*   regime = (const int*)d_in[1];
  const float* ew1  = (const float*)d_in[3];
  const float* eb1  = (const float*)d_in[4];
  const float* lng  = (const float*)d_in[5];
  const float* lnb  = (const float*)d_in[6];
  const float* ew2  = (const float*)d_in[7];
  const float* eb2  = (const float*)d_in[8];
  const float* rw1  = (const float*)d_in[9];
  const float* rb1  = (const float*)d_in[10];
  const float* rw2  = (const float*)d_in[11];
  const float* rb2  = (const float*)d_in[12];
  const float* ipw  = (const float*)d_in[13];
  const float* ipb  = (const float*)d_in[14];
  const float* opw  = (const float*)d_in[15];
  const float* opb  = (const float*)d_in[16];
  const float* ang  = (const float*)d_in[17];
  const float* anb  = (const float*)d_in[18];
  float* out = (float*)d_out;

  char* ws = (char*)d_ws;
  // workspace layout (<= 166 MiB, overlays time-disjoint):
  int*   meta  = (int*)(ws);                        // @0
  int*   perm  = (int*)(ws + (16u << 10));
  int*   tki   = (int*)(ws + (32u << 10));
  float* tkw   = (float*)(ws + (48u << 10));
  int*   qrows = (int*)(ws + (64u << 10));
  float* rbias = (float*)(ws + (80u << 10));        // 32 KB
  short* ipwb  = (short*)(ws + (256u << 10));       // @0.25 MiB, 1.5 MiB
  short* opwb  = (short*)(ws + (1792u << 10));      // @1.75, 0.5 MiB
  short* xp    = (short*)(ws + (2304u << 10));      // @2.25, 2 MiB
  short* eo    = (short*)(ws + (4352u << 10));      // @4.25, 16 MiB (GEMM2 p0, then eo)
  short* hact  = (short*)(ws + (22ull << 20));      // @22, 64 MiB (part dead before GEMM1 writes)
  short* qkv   = (short*)(ws + (22ull << 20));      // @22, 32 MiB (after hact dead)
  short* qb    = (short*)(ws + (54ull << 20));      // @54, 4 MiB
  short* av    = (short*)(ws + (58ull << 20));      // @58, 4 MiB
  float* proj  = (float*)(ws + (62ull << 20));      // @62, 8 MiB
  float* part  = (float*)(ws + (70ull << 20));      // @70, 2 MiB logit partials [32][2048][8] (dead before GEMM1)
  short* wt    = (short*)(ws + (86ull << 20));      // @86, 64 MiB (router B' 32, then ew1t 64, then ew2t 64)
  short* xd    = (short*)(ws + (150ull << 20));     // @150, 8 MiB (router A'; dead after router gemm)
  short* p1    = (short*)(ws + (150ull << 20));     // @150, 16 MiB (GEMM2 partial 1; overlays dead xd)

  hipMemsetAsync(meta, 0, 1024, stream);
  k_count  <<<8, 256, 0, stream>>>(regime, meta);
  k_scan   <<<1, 64, 0, stream>>>(meta);
  k_scatter<<<8, 256, 0, stream>>>(regime, meta, perm);
  k_xsplit <<<CB, 256, 0, stream>>>(x, perm, xp, xd);
  k_cvt    <<<384, 256, 0, stream>>>(ipw, ipwb, 1536 * 512);
  k_cvt    <<<128, 256, 0, stream>>>(opw, opwb, 512 * 512);

  // fused router: split-bf16 MFMA (K'=2048 = [hi|hi|lo|lo]x[Whi|Wlo|Whi|Wlo], exact 4-term)
  // + relu + rw2 contraction in-epilogue -> logit partials
  k_rwt  <<<dim3(32, 8, CR), 256, 0, stream>>>(rw1, wt);
  k_rbias<<<dim3(8, CR), 256, 0, stream>>>(rw1, rb1, rbias);
  gemm_bf16<6, false><<<dim3(16, 16, CR), 256, 0, stream>>>(
      xd, 2048, wt, 2048, meta, 0, 2048, 1, CH, rbias, 0,
      nullptr, nullptr, part, nullptr, rw2, 0, 0);
  k_logits2<<<CB / 4, 256, 0, stream>>>(part, rb2, meta, perm, tki, tkw);
  k_qrows<<<16, 256, 0, stream>>>(tki, qrows);

  // expert GEMM1 (XCD-chunk swizzled 1-D grid): hact[e][i_sorted] = xp @ ew1t[r,e] + eb1
  k_cvt_t<<<dim3(32, 8, 32), 256, 0, stream>>>(ew1, wt, CD, CH);
  gemm_bf16<1, true><<<8192, 256, 0, stream>>>(
      xp, CD, wt, CD, meta, 0, CD, 1, CH, eb1, CH, hact, nullptr, nullptr, nullptr, nullptr, 16, 16);
  k_ln<<<CE * CB, 256, 0, stream>>>(hact, lng, lnb, meta);

  // expert GEMM2 (K-split x2, XCD-chunk swizzled): partials -> eo(p0)/p1, scattered by borig
  k_cvt_t<<<dim3(8, 32, 32), 256, 0, stream>>>(ew2, wt, CH, CO);
  gemm_bf16<2, true><<<4096, 256, 0, stream>>>(
      hact, CH, wt, CH, meta, 0, 1024, 2, CO, nullptr, 0, eo, p1, nullptr, perm, nullptr, 16, 4);
  k_eo<<<dim3(CB, CE), 256, 0, stream>>>(p1, eb2, x, regime, eo);

  // KV for all (b,e), XCD-chunk swizzled: qkv[row][1024] = eo @ ipwb[512:1536] + ipb[512:]
  gemm_bf16<3, true><<<1024, 256, 0, stream>>>(
      eo, CO, ipwb + (size_t)512 * 512, CO, nullptr, CB * CE, CO, 1, 1024, ipb + 512, 0,
      qkv, nullptr, nullptr, nullptr, nullptr, 128, 8);
  // Q only for selected experts: qb[b*2+j] = eo[qrows] @ ipwb[0:512] + ipb[:512]
  gemm_bf16<3, false><<<dim3(4, 32, 1), 256, 0, stream>>>(
      eo, CO, ipwb, CO, nullptr, CB * 2, CO, 1, CO, ipb, 0,
      qb, nullptr, nullptr, qrows, nullptr, 0, 0);

  k_attn<<<CB, 128, 0, stream>>>(qb, qkv, tki, av);

  // proj: proj[b*2+j] = av @ opwb + opb   (f32 out)
  gemm_bf16<4, false><<<dim3(4, 32, 1), 256, 0, stream>>>(
      av, CO, opwb, CO, nullptr, CB * 2, CO, 1, CO, opb, 0,
      nullptr, nullptr, proj, nullptr, nullptr, 0, 0);

  k_final<<<CB, 256, 0, stream>>>(eo, proj, tki, tkw, ang, anb, out);
  (void)in_sizes; (void)n_in; (void)out_size; (void)ws_size;
}